// Round 11
// baseline (413.849 us; speedup 1.0000x reference)
//
#include <hip/hip_runtime.h>
#include <hip/hip_bf16.h>

typedef unsigned short u16;
typedef unsigned int u32;
typedef short short8 __attribute__((ext_vector_type(8)));
typedef float f32x4 __attribute__((ext_vector_type(4)));

constexpr int BATCH = 32, L = 200, NUM_C = 256, NUM_D = 32, V = 128;
constexpr int G3 = 384;                 // 3*V
constexpr int KQ = 512;                 // Q row: 384 gx | 128 P
constexpr int ROWS = BATCH * L;         // 6400
constexpr int TP = 208;                 // padded t (13 tiles x 16)
constexpr int TCH = 50;                 // GRU->alpha time chunk
constexpr size_t ALPHA_OFF = 0;
constexpr size_t H_OFF = (size_t)ROWS * NUM_D;        // 204800
constexpr size_t C_OFF = H_OFF + (size_t)ROWS * V;    // 1024000

// cross-block pipeline flags (zeroed by k1 each launch; k1 precedes in-stream)
__device__ int g_hcnt[4];     // GRU blocks past time-chunk k (stores drained)
__device__ int g_cflag[32];   // per-batch: scan block done

__device__ inline u16 f2bf(float f) {
  __hip_bfloat16 h = __float2bfloat16(f);
  return __builtin_bit_cast(u16, h);
}
__device__ inline float bf2f(u16 u) { u32 x = ((u32)u) << 16; return __builtin_bit_cast(float, x); }

// convert 32 contiguous f32 -> 32 bf16 (dst 8B-aligned)
__device__ inline void cvt32(const float* __restrict__ src, u16* __restrict__ dst) {
#pragma unroll
  for (int j0 = 0; j0 < 32; j0 += 4) {
    const f32x4 v = *(const f32x4*)(src + j0);
    ushort4 s;
    s.x = f2bf(v[0]); s.y = f2bf(v[1]); s.z = f2bf(v[2]); s.w = f2bf(v[3]);
    *(ushort4*)(dst + j0) = s;
  }
}
// load 8 contiguous f32 -> bf16 MFMA fragment
__device__ inline short8 ldfrag(const float* __restrict__ p) {
  const f32x4 a = *(const f32x4*)p, b = *(const f32x4*)(p + 4);
  short8 s;
  s[0] = (short)f2bf(a[0]); s[1] = (short)f2bf(a[1]);
  s[2] = (short)f2bf(a[2]); s[3] = (short)f2bf(a[3]);
  s[4] = (short)f2bf(b[0]); s[5] = (short)f2bf(b[1]);
  s[6] = (short)f2bf(b[2]); s[7] = (short)f2bf(b[3]);
  return s;
}

// ---------------------------------------------------------------------------
// K1: Q[row, 0:384] = gru_in @ W_ih^T + b_ih ; Q[row, 384:512] = P (mem MLP)
//     (also zeroes the k23 pipeline flags)
// ---------------------------------------------------------------------------
__global__ __launch_bounds__(256) void k1(
    const int* __restrict__ c_seq, const int* __restrict__ d_seq,
    const float* __restrict__ r_seq, const float* __restrict__ X,
    const float* __restrict__ v_r, const float* __restrict__ W_ih,
    const float* __restrict__ W2a, const float* __restrict__ b_ih,
    const float* __restrict__ b2a, float* __restrict__ Qout)
{
  __shared__ __align__(16) u16 Als[64][144];
  __shared__ __align__(16) u16 Bls[64][144];
  const int tid = threadIdx.x;
  if (blockIdx.x == 0 && blockIdx.y == 0 && tid == 0) {
#pragma unroll
    for (int i = 0; i < 4; ++i) g_hcnt[i] = 0;
#pragma unroll
    for (int i = 0; i < 32; ++i) g_cflag[i] = 0;
  }
  const int mt = blockIdx.x, nt = blockIdx.y;
  const int lane = tid & 63, w = tid >> 6;
  const int q = lane >> 4, m = lane & 15;

  f32x4 acc[4];
#pragma unroll
  for (int i = 0; i < 4; ++i) acc[i] = (f32x4)0.0f;

  const int r0 = tid >> 2;          // 0..63 staged row
  const int kc = (tid & 3) * 32;    // k chunk
  const int rowg = mt * 64 + r0;    // global (b,t) row
  const int gcolB = nt * 64 + r0;   // global output col staged as B row

  for (int s = 0; s < 2; ++s) {     // two K-stages of 128
    if (s) __syncthreads();
    if (s == 0) {
      const int idx = c_seq[rowg] + NUM_C * d_seq[rowg];
      cvt32(X + (size_t)idx * V + kc, &Als[r0][kc]);
    } else {
      const float rv = r_seq[rowg];
#pragma unroll
      for (int j0 = 0; j0 < 32; j0 += 4) {
        const f32x4 v = *(const f32x4*)(v_r + kc + j0);
        ushort4 sv;
        sv.x = f2bf(rv * v[0]); sv.y = f2bf(rv * v[1]);
        sv.z = f2bf(rv * v[2]); sv.w = f2bf(rv * v[3]);
        *(ushort4*)&Als[r0][kc + j0] = sv;
      }
    }
    {
      const float* src = (gcolB < G3)
        ? (W_ih + (size_t)gcolB * 256 + s * 128 + kc)
        : (W2a + (size_t)(gcolB - G3) * G3 + V + s * 128 + kc);
      cvt32(src, &Bls[r0][kc]);
    }
    __syncthreads();
#pragma unroll
    for (int c = 0; c < 4; ++c) {
      const short8 af = *(const short8*)&Als[w * 16 + m][32 * c + 8 * q];
#pragma unroll
      for (int i = 0; i < 4; ++i) {
        const short8 bf = *(const short8*)&Bls[i * 16 + m][32 * c + 8 * q];
        acc[i] = __builtin_amdgcn_mfma_f32_16x16x32_bf16(af, bf, acc[i], 0, 0, 0);
      }
    }
  }
#pragma unroll
  for (int i = 0; i < 4; ++i) {
    const int col = nt * 64 + i * 16 + m;
    const float bias = (col < G3) ? b_ih[col] : b2a[col - G3];
#pragma unroll
    for (int r = 0; r < 4; ++r) {
      const int rowo = mt * 64 + w * 16 + q * 4 + r;
      Qout[(size_t)rowo * KQ + col] = acc[i][r] + bias;
    }
  }
}

// ---------------------------------------------------------------------------
// K23 (fused, flag-pipelined) — PRIVATE-CU layout (LDS>80KB -> 1 block/CU;
// 242 blocks <= 256 CUs -> all resident by capacity, spin-wait safe):
//   blocks   0.. 31: GRU batch b; signals g_hcnt[k] after draining the
//                    stores of time-chunk k (t in [50k,50k+50)) -- lets the
//                    alpha GEMM run UNDER the remaining GRU steps.
//   blocks  32.. 63: memory-scan parallel fixpoint -> g_cflag[b]=1
//   blocks  64..191: C_seq forward-fill (4/batch), waits g_cflag[b]
//   blocks 192..241: alpha GEMM, 2 tile-jobs each in CHUNK-MAJOR order;
//                    job j: chunk k=j/25, tile j%25 (64 rows enumerated
//                    b-major inside the chunk), waits g_hcnt[k]==32.
// ---------------------------------------------------------------------------
union ShK23 {
  struct { u16 h_bf[2][V]; } g;
  struct {
    int cb[TP]; int db[TP]; int sp[TP];
    float nr[TP][36];                 // n(t) rows; stride 36 (16B-aligned)
    float u[V];
    int maxd;
  } s;
  struct { int cb[L]; float stage[L][NUM_D]; } f;
  struct { u16 hls[64][144]; u16 hid[64][144]; } a;
  struct { char p[84000]; } pad;      // forces 1 block/CU (84KB > 160KB/2)
};

__global__ __launch_bounds__(256, 1) void k23(
    const int* __restrict__ c_seq, const int* __restrict__ d_seq,
    const float* __restrict__ W_hh, const float* __restrict__ b_hh,
    const float* __restrict__ W2a, const float* __restrict__ v_beta,
    const float* __restrict__ W2b, const float* __restrict__ b2b,
    const float* __restrict__ W1a, const float* __restrict__ b1a,
    const float* __restrict__ W1b, const float* __restrict__ b1b,
    const float* __restrict__ Q, float* __restrict__ out)
{
  __shared__ __align__(16) ShK23 sh;
  const int tid = threadIdx.x;
  const int l = tid & 63, w = tid >> 6, q = l >> 4, m = l & 15;
  const int blk = blockIdx.x;

  if (blk < 32) {
    // ---------------- GRU (round-7 loop + chunk signaling) ----------------
    const int b = blk;
    if (tid < V) sh.g.h_bf[0][tid] = 0;
    __syncthreads();
    short8 wf[6][4];
    float bhh[6]; int gcol[6];
#pragma unroll
    for (int i = 0; i < 6; ++i) {
      const int g = (w + 4 * i) * 16 + m;
      gcol[i] = g;
      bhh[i] = b_hh[g];
#pragma unroll
      for (int c = 0; c < 4; ++c)
        wf[i][c] = ldfrag(W_hh + (size_t)g * V + 32 * c + 8 * q);
    }
    const float* Qb = Q + (size_t)b * L * KQ;
    float* outh = out + H_OFF + (size_t)b * L * V;
    const int vi0 = 16 * w + m, vi1 = 64 + 16 * w + m;
    float hold[2] = {0.f, 0.f};
    float hst[2] = {0.f, 0.f};
    const f32x4 z4 = (f32x4)0.0f;
    float gxA[6], gxB[6];
#pragma unroll
    for (int i = 0; i < 6; ++i) gxA[i] = Qb[gcol[i]];
#pragma unroll
    for (int i = 0; i < 6; ++i) gxB[i] = Qb[KQ + gcol[i]];

    auto step = [&](int t, float (&gx)[6]) {
      const int rs = t & 1, wsl = rs ^ 1;
      short8 af[4];
#pragma unroll
      for (int c = 0; c < 4; ++c)
        af[c] = *(const short8*)&sh.g.h_bf[rs][32 * c + 8 * q];
      if (t > 0 && q == 0) {
        outh[(size_t)(t - 1) * V + vi0] = hst[0];
        outh[(size_t)(t - 1) * V + vi1] = hst[1];
      }
      f32x4 acc[6];
#pragma unroll
      for (int i = 0; i < 6; ++i)
        acc[i] = __builtin_amdgcn_mfma_f32_16x16x32_bf16(af[0], wf[i][0], z4, 0, 0, 0);
#pragma unroll
      for (int c = 1; c < 4; ++c)
#pragma unroll
        for (int i = 0; i < 6; ++i)
          acc[i] = __builtin_amdgcn_mfma_f32_16x16x32_bf16(af[c], wf[i][c], acc[i], 0, 0, 0);
      float hnew[2];
#pragma unroll
      for (int s = 0; s < 2; ++s) {
        const float xr = gx[0 + s] + acc[0 + s][0] + bhh[0 + s];
        const float xz = gx[2 + s] + acc[2 + s][0] + bhh[2 + s];
        const float ghn = acc[4 + s][0] + bhh[4 + s];
        const float r = 1.f / (1.f + __expf(-xr));
        const float z = 1.f / (1.f + __expf(-xz));
        const float xn = gx[4 + s] + r * ghn;
        const float e = __expf(2.f * xn);
        const float n = 1.f - 2.f / (e + 1.f);     // tanh(xn)
        hnew[s] = (1.f - z) * n + z * hold[s];
      }
      if (q == 0) {
        sh.g.h_bf[wsl][vi0] = f2bf(hnew[0]);
        sh.g.h_bf[wsl][vi1] = f2bf(hnew[1]);
      }
      hold[0] = hnew[0]; hold[1] = hnew[1];
      hst[0] = hnew[0]; hst[1] = hnew[1];
      if (t + 2 < L) {
        const float* Qr = Qb + (size_t)(t + 2) * KQ;
#pragma unroll
        for (int i = 0; i < 6; ++i) gx[i] = Qr[gcol[i]];
      }
      __builtin_amdgcn_s_waitcnt(0xc07f);   // lgkmcnt(0)
      __builtin_amdgcn_s_barrier();
      // chunk signal: at t=50k+50 the stores covering chunk k have been
      // issued (h(t-1) stored at the top of step t); drain + release.
      if (t > 0 && t % TCH == 0) {
        __builtin_amdgcn_s_waitcnt(0x0f70);   // vmcnt(0)
        __syncthreads();
        __threadfence();
        if (tid == 0) atomicAdd(&g_hcnt[t / TCH - 1], 1);
      }
    };

    for (int t = 0; t < L; t += 2) {
      step(t, gxA);
      step(t + 1, gxB);
    }
    if (q == 0) {
      outh[(size_t)(L - 1) * V + vi0] = hst[0];
      outh[(size_t)(L - 1) * V + vi1] = hst[1];
    }
    __builtin_amdgcn_s_waitcnt(0x0f70);       // vmcnt(0)
    __syncthreads();
    __threadfence();
    if (tid == 0) atomicAdd(&g_hcnt[3], 1);
  } else if (blk < 64) {
    // ---------------- memory scan: parallel fixpoint (round-8) ------------
    const int b = blk - 32;
    for (int i = tid; i < TP; i += 256) {
      int c = -1, d = 0;
      if (i < L) { c = c_seq[b * L + i]; d = d_seq[b * L + i]; }
      sh.s.cb[i] = c; sh.s.db[i] = d; sh.s.sp[i] = -1;
    }
    if (tid < V) {
      float a = 0.f;
      const float* wr = W2a + (size_t)tid * G3;
      for (int k = 0; k < V; ++k) a += wr[k] * v_beta[k];
      sh.s.u[tid] = a;
    }
    if (tid == 0) sh.s.maxd = 0;
    __syncthreads();
    {
      const int c = tid;               // 256 threads == NUM_C
      int prev = -1;
      for (int t4 = 0; t4 < L; t4 += 4) {
        const int4 v = *(const int4*)&sh.s.cb[t4];
        if (v.x == c) { sh.s.sp[t4 + 0] = prev; prev = t4 + 0; }
        if (v.y == c) { sh.s.sp[t4 + 1] = prev; prev = t4 + 1; }
        if (v.z == c) { sh.s.sp[t4 + 2] = prev; prev = t4 + 2; }
        if (v.w == c) { sh.s.sp[t4 + 3] = prev; prev = t4 + 3; }
      }
    }
    __syncthreads();
    {
      int dmx = 0;
      for (int t = tid; t < L; t += 256) {
        int dd = 0, s = sh.s.sp[t];
        while (s >= 0) { ++dd; s = sh.s.sp[s]; }
        dmx = dmx > dd ? dmx : dd;
      }
      atomicMax(&sh.s.maxd, dmx);
    }
    __syncthreads();
    const int rounds = sh.s.maxd + 1;
    float ureg[4][8];
#pragma unroll
    for (int c = 0; c < 4; ++c)
#pragma unroll
      for (int j = 0; j < 8; ++j) ureg[c][j] = sh.s.u[32 * c + 8 * q + j];
    short8 wbf[2][4];
    float bb[2];
#pragma unroll
    for (int tt = 0; tt < 2; ++tt) {
#pragma unroll
      for (int c = 0; c < 4; ++c)
        wbf[tt][c] = ldfrag(W2b + (size_t)(tt * 16 + m) * V + 32 * c + 8 * q);
      bb[tt] = b2b[tt * 16 + m];
    }
    const f32x4 z4 = (f32x4)0.0f;
    for (int rd = 0; rd < rounds; ++rd) {
      for (int ti = w; ti < 13; ti += 4) {
        const int t0 = ti * 16;
        const int tt = t0 + m;
        const bool ok = tt < L;
        const int spv = ok ? sh.s.sp[tt] : -1;
        const int dbv = ok ? sh.s.db[tt] : 0;
        const float beta = (spv >= 0) ? sh.s.nr[spv][dbv] : 0.f;
        const float* pr = Q + ((size_t)b * L + tt) * KQ + G3 + 8 * q;
        short8 af[4];
#pragma unroll
        for (int c = 0; c < 4; ++c) {
          const f32x4 p0 = ok ? *(const f32x4*)(pr + 32 * c) : (f32x4)0.0f;
          const f32x4 p1 = ok ? *(const f32x4*)(pr + 32 * c + 4) : (f32x4)0.0f;
          short8 a;
#pragma unroll
          for (int j = 0; j < 8; ++j) {
            const float pv = (j < 4) ? p0[j] : p1[j - 4];
            a[j] = (short)f2bf(fmaxf(beta * ureg[c][j] + pv, 0.f));
          }
          af[c] = a;
        }
        f32x4 a0 = z4, a1 = z4;
#pragma unroll
        for (int c = 0; c < 4; ++c) {
          a0 = __builtin_amdgcn_mfma_f32_16x16x32_bf16(af[c], wbf[0][c], a0, 0, 0, 0);
          a1 = __builtin_amdgcn_mfma_f32_16x16x32_bf16(af[c], wbf[1][c], a1, 0, 0, 0);
        }
#pragma unroll
        for (int r = 0; r < 4; ++r) {
          const int tr = t0 + q * 4 + r;
          sh.s.nr[tr][m]      = a0[r] + bb[0];
          sh.s.nr[tr][16 + m] = a1[r] + bb[1];
        }
      }
      __syncthreads();
    }
    float* outc = out + C_OFF + (size_t)b * L * (NUM_C * NUM_D);
    const int j4 = (tid & 7) * 4;
    for (int t = tid >> 3; t < L; t += 32) {
      const int c = sh.s.cb[t];
      float* oc = outc + (size_t)t * (NUM_C * NUM_D) + c * NUM_D + j4;
      *(f32x4*)oc = *(const f32x4*)&sh.s.nr[t][j4];
    }
    __threadfence();
    __syncthreads();
    if (tid == 0) atomicExch(&g_cflag[b], 1);
  } else if (blk < 192) {
    // ---------------- C_seq forward-fill (4 blocks/batch, 64 c's each) ----
    const int blk2 = blk - 64;
    const int b = blk2 >> 2, cbase = (blk2 & 3) * 64;
    if (tid < L) sh.f.cb[tid] = c_seq[b * L + tid];
    if (tid == 0) {
      while (atomicAdd(&g_cflag[b], 0) == 0) __builtin_amdgcn_s_sleep(32);
    }
    __syncthreads();
    __threadfence();
    // phase A: stage this block's update rows
    if (tid < L) {
      const int c = sh.f.cb[tid];
      if (c >= cbase && c < cbase + 64) {
        const float* src = out + C_OFF + ((size_t)b * L + tid) * (NUM_C * NUM_D) + (size_t)c * NUM_D;
#pragma unroll
        for (int j = 0; j < 8; ++j)
          *(f32x4*)&sh.f.stage[tid][j * 4] = *(const f32x4*)(src + j * 4);
      }
    }
    __syncthreads();
    // phase B: pure store loop (each thread owns 8 floats of one c-row)
    const int cl = tid >> 2, dq = (tid & 3) * 8;
    const int myc = cbase + cl;
    float* base = out + C_OFF + (size_t)b * L * (NUM_C * NUM_D) + (size_t)myc * NUM_D + dq;
    f32x4 cur0 = (f32x4)0.0f, cur1 = (f32x4)0.0f;
    for (int t = 0; t < L; ++t) {
      if (sh.f.cb[t] == myc) {
        cur0 = *(const f32x4*)&sh.f.stage[t][dq];
        cur1 = *(const f32x4*)&sh.f.stage[t][dq + 4];
      }
      *(f32x4*)base = cur0;
      *(f32x4*)(base + 4) = cur1;
      base += NUM_C * NUM_D;
    }
  } else {
    // ---------------- alpha GEMM: 2 chunk-major tile-jobs per block -------
    for (int jj = 0; jj < 2; ++jj) {
      const int job = (blk - 192) * 2 + jj;   // 0..99
      const int ck = job / 25, tile = job % 25;
      if (tid == 0) {
        while (atomicAdd(&g_hcnt[ck], 0) < 32) __builtin_amdgcn_s_sleep(32);
      }
      __syncthreads();
      __threadfence();
      // stage 64 h rows of chunk ck (idx = b*50 + s, row = b*200 + ck*50 + s)
      {
        const int r0 = tid >> 2, kc = (tid & 3) * 32;
        const int idx = tile * 64 + r0;
        const int bb = idx / TCH, ss = idx % TCH;
        const int row = bb * L + ck * TCH + ss;
        cvt32(out + H_OFF + (size_t)row * V + kc, &sh.a.hls[r0][kc]);
      }
      __syncthreads();
      f32x4 acc1[8];
#pragma unroll
      for (int i = 0; i < 8; ++i) acc1[i] = (f32x4)0.0f;
#pragma unroll
      for (int c = 0; c < 4; ++c) {
        const short8 af = *(const short8*)&sh.a.hls[w * 16 + m][32 * c + 8 * q];
#pragma unroll
        for (int i = 0; i < 8; ++i) {
          const short8 bf = ldfrag(W1a + (size_t)(i * 16 + m) * V + 32 * c + 8 * q);
          acc1[i] = __builtin_amdgcn_mfma_f32_16x16x32_bf16(af, bf, acc1[i], 0, 0, 0);
        }
      }
#pragma unroll
      for (int i = 0; i < 8; ++i) {
        const int col = i * 16 + m;
        const float bias = b1a[col];
#pragma unroll
        for (int r = 0; r < 4; ++r)
          sh.a.hid[w * 16 + q * 4 + r][col] = f2bf(fmaxf(acc1[i][r] + bias, 0.f));
      }
      __syncthreads();
      f32x4 acc2[2];
      acc2[0] = (f32x4)0.0f; acc2[1] = (f32x4)0.0f;
#pragma unroll
      for (int c = 0; c < 4; ++c) {
        const short8 af = *(const short8*)&sh.a.hid[w * 16 + m][32 * c + 8 * q];
#pragma unroll
        for (int tt = 0; tt < 2; ++tt) {
          const short8 bf = ldfrag(W1b + (size_t)(tt * 16 + m) * V + 32 * c + 8 * q);
          acc2[tt] = __builtin_amdgcn_mfma_f32_16x16x32_bf16(af, bf, acc2[tt], 0, 0, 0);
        }
      }
#pragma unroll
      for (int tt = 0; tt < 2; ++tt) {
        const int col = tt * 16 + m;
        const float bias = b1b[col];
#pragma unroll
        for (int r = 0; r < 4; ++r) {
          const int idx = tile * 64 + w * 16 + q * 4 + r;
          const int bb = idx / TCH, ss = idx % TCH;
          const int row = bb * L + ck * TCH + ss;
          out[ALPHA_OFF + (size_t)row * NUM_D + col] = acc2[tt][r] + bias;
        }
      }
      __syncthreads();   // protect LDS reuse across jobs
    }
  }
}

extern "C" void kernel_launch(void* const* d_in, const int* in_sizes, int n_in,
                              void* d_out, int out_size, void* d_ws, size_t ws_size,
                              hipStream_t stream) {
  const int*   c_seq  = (const int*)d_in[0];
  const int*   d_seq  = (const int*)d_in[1];
  const float* r_seq  = (const float*)d_in[2];
  const float* X      = (const float*)d_in[3];
  const float* v_r    = (const float*)d_in[4];
  const float* v_beta = (const float*)d_in[5];
  const float* W_ih   = (const float*)d_in[6];
  const float* W_hh   = (const float*)d_in[7];
  const float* b_ih   = (const float*)d_in[8];
  const float* b_hh   = (const float*)d_in[9];
  const float* W1a    = (const float*)d_in[10];
  const float* b1a    = (const float*)d_in[11];
  const float* W1b    = (const float*)d_in[12];
  const float* b1b    = (const float*)d_in[13];
  const float* W2a    = (const float*)d_in[14];
  const float* b2a    = (const float*)d_in[15];
  const float* W2b    = (const float*)d_in[16];
  const float* b2b    = (const float*)d_in[17];
  float* out = (float*)d_out;
  float* Q = (float*)d_ws;

  k1<<<dim3(100, 8), 256, 0, stream>>>(c_seq, d_seq, r_seq, X, v_r, W_ih, W2a, b_ih, b2a, Q);
  k23<<<242, 256, 0, stream>>>(c_seq, d_seq, W_hh, b_hh, W2a, v_beta, W2b, b2b,
                               W1a, b1a, W1b, b1b, Q, out);
}

// Round 12
// 383.400 us; speedup vs baseline: 1.0794x; 1.0794x over previous
//
#include <hip/hip_runtime.h>
#include <hip/hip_bf16.h>

typedef unsigned short u16;
typedef unsigned int u32;
typedef short short8 __attribute__((ext_vector_type(8)));
typedef float f32x4 __attribute__((ext_vector_type(4)));

constexpr int BATCH = 32, L = 200, NUM_C = 256, NUM_D = 32, V = 128;
constexpr int G3 = 384;                 // 3*V
constexpr int KQ = 512;                 // Q row: 384 gx | 128 P
constexpr int ROWS = BATCH * L;         // 6400
constexpr int TP = 208;                 // padded t (13 tiles x 16)
constexpr size_t ALPHA_OFF = 0;
constexpr size_t H_OFF = (size_t)ROWS * NUM_D;        // 204800
constexpr size_t C_OFF = H_OFF + (size_t)ROWS * V;    // 1024000

// cross-block pipeline flags (zeroed by k1 each launch; k1 precedes in-stream)
__device__ int g_gcnt;        // GRU blocks finished
__device__ int g_cflag[32];   // per-batch: scan block done

__device__ inline u16 f2bf(float f) {
  __hip_bfloat16 h = __float2bfloat16(f);
  return __builtin_bit_cast(u16, h);
}
__device__ inline float bf2f(u16 u) { u32 x = ((u32)u) << 16; return __builtin_bit_cast(float, x); }

// convert 32 contiguous f32 -> 32 bf16 (dst 8B-aligned)
__device__ inline void cvt32(const float* __restrict__ src, u16* __restrict__ dst) {
#pragma unroll
  for (int j0 = 0; j0 < 32; j0 += 4) {
    const f32x4 v = *(const f32x4*)(src + j0);
    ushort4 s;
    s.x = f2bf(v[0]); s.y = f2bf(v[1]); s.z = f2bf(v[2]); s.w = f2bf(v[3]);
    *(ushort4*)(dst + j0) = s;
  }
}
// load 8 contiguous f32 -> bf16 MFMA fragment
__device__ inline short8 ldfrag(const float* __restrict__ p) {
  const f32x4 a = *(const f32x4*)p, b = *(const f32x4*)(p + 4);
  short8 s;
  s[0] = (short)f2bf(a[0]); s[1] = (short)f2bf(a[1]);
  s[2] = (short)f2bf(a[2]); s[3] = (short)f2bf(a[3]);
  s[4] = (short)f2bf(b[0]); s[5] = (short)f2bf(b[1]);
  s[6] = (short)f2bf(b[2]); s[7] = (short)f2bf(b[3]);
  return s;
}

// ---------------------------------------------------------------------------
// K1: Q[row, 0:384] = gru_in @ W_ih^T + b_ih ; Q[row, 384:512] = P (mem MLP)
//     (also zeroes the k23 pipeline flags)
// ---------------------------------------------------------------------------
__global__ __launch_bounds__(256) void k1(
    const int* __restrict__ c_seq, const int* __restrict__ d_seq,
    const float* __restrict__ r_seq, const float* __restrict__ X,
    const float* __restrict__ v_r, const float* __restrict__ W_ih,
    const float* __restrict__ W2a, const float* __restrict__ b_ih,
    const float* __restrict__ b2a, float* __restrict__ Qout)
{
  __shared__ __align__(16) u16 Als[64][144];
  __shared__ __align__(16) u16 Bls[64][144];
  const int tid = threadIdx.x;
  if (blockIdx.x == 0 && blockIdx.y == 0 && tid == 0) {
    g_gcnt = 0;
#pragma unroll
    for (int i = 0; i < 32; ++i) g_cflag[i] = 0;
  }
  const int mt = blockIdx.x, nt = blockIdx.y;
  const int lane = tid & 63, w = tid >> 6;
  const int q = lane >> 4, m = lane & 15;

  f32x4 acc[4];
#pragma unroll
  for (int i = 0; i < 4; ++i) acc[i] = (f32x4)0.0f;

  const int r0 = tid >> 2;          // 0..63 staged row
  const int kc = (tid & 3) * 32;    // k chunk
  const int rowg = mt * 64 + r0;    // global (b,t) row
  const int gcolB = nt * 64 + r0;   // global output col staged as B row

  for (int s = 0; s < 2; ++s) {     // two K-stages of 128
    if (s) __syncthreads();
    if (s == 0) {
      const int idx = c_seq[rowg] + NUM_C * d_seq[rowg];
      cvt32(X + (size_t)idx * V + kc, &Als[r0][kc]);
    } else {
      const float rv = r_seq[rowg];
#pragma unroll
      for (int j0 = 0; j0 < 32; j0 += 4) {
        const f32x4 v = *(const f32x4*)(v_r + kc + j0);
        ushort4 sv;
        sv.x = f2bf(rv * v[0]); sv.y = f2bf(rv * v[1]);
        sv.z = f2bf(rv * v[2]); sv.w = f2bf(rv * v[3]);
        *(ushort4*)&Als[r0][kc + j0] = sv;
      }
    }
    {
      const float* src = (gcolB < G3)
        ? (W_ih + (size_t)gcolB * 256 + s * 128 + kc)
        : (W2a + (size_t)(gcolB - G3) * G3 + V + s * 128 + kc);
      cvt32(src, &Bls[r0][kc]);
    }
    __syncthreads();
#pragma unroll
    for (int c = 0; c < 4; ++c) {
      const short8 af = *(const short8*)&Als[w * 16 + m][32 * c + 8 * q];
#pragma unroll
      for (int i = 0; i < 4; ++i) {
        const short8 bf = *(const short8*)&Bls[i * 16 + m][32 * c + 8 * q];
        acc[i] = __builtin_amdgcn_mfma_f32_16x16x32_bf16(af, bf, acc[i], 0, 0, 0);
      }
    }
  }
#pragma unroll
  for (int i = 0; i < 4; ++i) {
    const int col = nt * 64 + i * 16 + m;
    const float bias = (col < G3) ? b_ih[col] : b2a[col - G3];
#pragma unroll
    for (int r = 0; r < 4; ++r) {
      const int rowo = mt * 64 + w * 16 + q * 4 + r;
      Qout[(size_t)rowo * KQ + col] = acc[i][r] + bias;
    }
  }
}

// ---------------------------------------------------------------------------
// K23 (fused, flag-pipelined) — PRIVATE-CU layout (LDS>80KB -> 1 block/CU;
// 192 blocks <= 256 CUs -> all resident by capacity, spin-wait safe):
//   blocks   0.. 31: GRU batch b (round-7/10 proven loop, UNTOUCHED) -> g_gcnt++
//   blocks  32.. 63: memory-scan parallel fixpoint -> g_cflag[b]=1
//   blocks  64..191: C_seq forward-fill (4/batch), waits g_cflag[b];
//                    THEN blocks 64..163 each run ONE 64-row alpha tile
//                    (job = blk-64) after waiting g_gcnt==32.
// vs r10: alpha tail is 100 parallel single-job blocks (was 50 blocks x 2
// sequential jobs) -> tail halves; GRU loop byte-identical to the 381us best.
// ---------------------------------------------------------------------------
union ShK23 {
  struct { u16 h_bf[2][V]; } g;
  struct {
    int cb[TP]; int db[TP]; int sp[TP];
    float nr[TP][36];                 // n(t) rows; stride 36 (16B-aligned)
    float u[V];
    int maxd;
  } s;
  struct { int cb[L]; float stage[L][NUM_D]; } f;
  struct { u16 hls[64][144]; u16 hid[64][144]; } a;
  struct { char p[84000]; } pad;      // forces 1 block/CU (84KB > 160KB/2)
};

__global__ __launch_bounds__(256, 1) void k23(
    const int* __restrict__ c_seq, const int* __restrict__ d_seq,
    const float* __restrict__ W_hh, const float* __restrict__ b_hh,
    const float* __restrict__ W2a, const float* __restrict__ v_beta,
    const float* __restrict__ W2b, const float* __restrict__ b2b,
    const float* __restrict__ W1a, const float* __restrict__ b1a,
    const float* __restrict__ W1b, const float* __restrict__ b1b,
    const float* __restrict__ Q, float* __restrict__ out)
{
  __shared__ __align__(16) ShK23 sh;
  const int tid = threadIdx.x;
  const int l = tid & 63, w = tid >> 6, q = l >> 4, m = l & 15;
  const int blk = blockIdx.x;

  if (blk < 32) {
    // ---------------- GRU (round-10 version, verbatim) --------------------
    const int b = blk;
    if (tid < V) sh.g.h_bf[0][tid] = 0;
    __syncthreads();
    short8 wf[6][4];
    float bhh[6]; int gcol[6];
#pragma unroll
    for (int i = 0; i < 6; ++i) {
      const int g = (w + 4 * i) * 16 + m;
      gcol[i] = g;
      bhh[i] = b_hh[g];
#pragma unroll
      for (int c = 0; c < 4; ++c)
        wf[i][c] = ldfrag(W_hh + (size_t)g * V + 32 * c + 8 * q);
    }
    const float* Qb = Q + (size_t)b * L * KQ;
    float* outh = out + H_OFF + (size_t)b * L * V;
    const int vi0 = 16 * w + m, vi1 = 64 + 16 * w + m;
    float hold[2] = {0.f, 0.f};
    float hst[2] = {0.f, 0.f};
    const f32x4 z4 = (f32x4)0.0f;
    float gxA[6], gxB[6];
#pragma unroll
    for (int i = 0; i < 6; ++i) gxA[i] = Qb[gcol[i]];
#pragma unroll
    for (int i = 0; i < 6; ++i) gxB[i] = Qb[KQ + gcol[i]];

    auto step = [&](int t, float (&gx)[6]) {
      const int rs = t & 1, wsl = rs ^ 1;
      short8 af[4];
#pragma unroll
      for (int c = 0; c < 4; ++c)
        af[c] = *(const short8*)&sh.g.h_bf[rs][32 * c + 8 * q];
      if (t > 0 && q == 0) {
        outh[(size_t)(t - 1) * V + vi0] = hst[0];
        outh[(size_t)(t - 1) * V + vi1] = hst[1];
      }
      f32x4 acc[6];
#pragma unroll
      for (int i = 0; i < 6; ++i)
        acc[i] = __builtin_amdgcn_mfma_f32_16x16x32_bf16(af[0], wf[i][0], z4, 0, 0, 0);
#pragma unroll
      for (int c = 1; c < 4; ++c)
#pragma unroll
        for (int i = 0; i < 6; ++i)
          acc[i] = __builtin_amdgcn_mfma_f32_16x16x32_bf16(af[c], wf[i][c], acc[i], 0, 0, 0);
      float hnew[2];
#pragma unroll
      for (int s = 0; s < 2; ++s) {
        const float xr = gx[0 + s] + acc[0 + s][0] + bhh[0 + s];
        const float xz = gx[2 + s] + acc[2 + s][0] + bhh[2 + s];
        const float ghn = acc[4 + s][0] + bhh[4 + s];
        const float r = 1.f / (1.f + __expf(-xr));
        const float z = 1.f / (1.f + __expf(-xz));
        const float xn = gx[4 + s] + r * ghn;
        const float e = __expf(2.f * xn);
        const float n = 1.f - 2.f / (e + 1.f);     // tanh(xn)
        hnew[s] = (1.f - z) * n + z * hold[s];
      }
      if (q == 0) {
        sh.g.h_bf[wsl][vi0] = f2bf(hnew[0]);
        sh.g.h_bf[wsl][vi1] = f2bf(hnew[1]);
      }
      hold[0] = hnew[0]; hold[1] = hnew[1];
      hst[0] = hnew[0]; hst[1] = hnew[1];
      if (t + 2 < L) {
        const float* Qr = Qb + (size_t)(t + 2) * KQ;
#pragma unroll
        for (int i = 0; i < 6; ++i) gx[i] = Qr[gcol[i]];
      }
      __builtin_amdgcn_s_waitcnt(0xc07f);   // lgkmcnt(0)
      __builtin_amdgcn_s_barrier();
    };

    for (int t = 0; t < L; t += 2) {
      step(t, gxA);
      step(t + 1, gxB);
    }
    if (q == 0) {
      outh[(size_t)(L - 1) * V + vi0] = hst[0];
      outh[(size_t)(L - 1) * V + vi1] = hst[1];
    }
    __threadfence();
    __syncthreads();
    if (tid == 0) atomicAdd(&g_gcnt, 1);
  } else if (blk < 64) {
    // ---------------- memory scan: parallel fixpoint (round-8) ------------
    const int b = blk - 32;
    for (int i = tid; i < TP; i += 256) {
      int c = -1, d = 0;
      if (i < L) { c = c_seq[b * L + i]; d = d_seq[b * L + i]; }
      sh.s.cb[i] = c; sh.s.db[i] = d; sh.s.sp[i] = -1;
    }
    if (tid < V) {
      float a = 0.f;
      const float* wr = W2a + (size_t)tid * G3;
      for (int k = 0; k < V; ++k) a += wr[k] * v_beta[k];
      sh.s.u[tid] = a;
    }
    if (tid == 0) sh.s.maxd = 0;
    __syncthreads();
    {
      const int c = tid;               // 256 threads == NUM_C
      int prev = -1;
      for (int t4 = 0; t4 < L; t4 += 4) {
        const int4 v = *(const int4*)&sh.s.cb[t4];
        if (v.x == c) { sh.s.sp[t4 + 0] = prev; prev = t4 + 0; }
        if (v.y == c) { sh.s.sp[t4 + 1] = prev; prev = t4 + 1; }
        if (v.z == c) { sh.s.sp[t4 + 2] = prev; prev = t4 + 2; }
        if (v.w == c) { sh.s.sp[t4 + 3] = prev; prev = t4 + 3; }
      }
    }
    __syncthreads();
    {
      int dmx = 0;
      for (int t = tid; t < L; t += 256) {
        int dd = 0, s = sh.s.sp[t];
        while (s >= 0) { ++dd; s = sh.s.sp[s]; }
        dmx = dmx > dd ? dmx : dd;
      }
      atomicMax(&sh.s.maxd, dmx);
    }
    __syncthreads();
    const int rounds = sh.s.maxd + 1;
    float ureg[4][8];
#pragma unroll
    for (int c = 0; c < 4; ++c)
#pragma unroll
      for (int j = 0; j < 8; ++j) ureg[c][j] = sh.s.u[32 * c + 8 * q + j];
    short8 wbf[2][4];
    float bb[2];
#pragma unroll
    for (int tt = 0; tt < 2; ++tt) {
#pragma unroll
      for (int c = 0; c < 4; ++c)
        wbf[tt][c] = ldfrag(W2b + (size_t)(tt * 16 + m) * V + 32 * c + 8 * q);
      bb[tt] = b2b[tt * 16 + m];
    }
    const f32x4 z4 = (f32x4)0.0f;
    for (int rd = 0; rd < rounds; ++rd) {
      for (int ti = w; ti < 13; ti += 4) {
        const int t0 = ti * 16;
        const int tt = t0 + m;
        const bool ok = tt < L;
        const int spv = ok ? sh.s.sp[tt] : -1;
        const int dbv = ok ? sh.s.db[tt] : 0;
        const float beta = (spv >= 0) ? sh.s.nr[spv][dbv] : 0.f;
        const float* pr = Q + ((size_t)b * L + tt) * KQ + G3 + 8 * q;
        short8 af[4];
#pragma unroll
        for (int c = 0; c < 4; ++c) {
          const f32x4 p0 = ok ? *(const f32x4*)(pr + 32 * c) : (f32x4)0.0f;
          const f32x4 p1 = ok ? *(const f32x4*)(pr + 32 * c + 4) : (f32x4)0.0f;
          short8 a;
#pragma unroll
          for (int j = 0; j < 8; ++j) {
            const float pv = (j < 4) ? p0[j] : p1[j - 4];
            a[j] = (short)f2bf(fmaxf(beta * ureg[c][j] + pv, 0.f));
          }
          af[c] = a;
        }
        f32x4 a0 = z4, a1 = z4;
#pragma unroll
        for (int c = 0; c < 4; ++c) {
          a0 = __builtin_amdgcn_mfma_f32_16x16x32_bf16(af[c], wbf[0][c], a0, 0, 0, 0);
          a1 = __builtin_amdgcn_mfma_f32_16x16x32_bf16(af[c], wbf[1][c], a1, 0, 0, 0);
        }
#pragma unroll
        for (int r = 0; r < 4; ++r) {
          const int tr = t0 + q * 4 + r;
          sh.s.nr[tr][m]      = a0[r] + bb[0];
          sh.s.nr[tr][16 + m] = a1[r] + bb[1];
        }
      }
      __syncthreads();
    }
    float* outc = out + C_OFF + (size_t)b * L * (NUM_C * NUM_D);
    const int j4 = (tid & 7) * 4;
    for (int t = tid >> 3; t < L; t += 32) {
      const int c = sh.s.cb[t];
      float* oc = outc + (size_t)t * (NUM_C * NUM_D) + c * NUM_D + j4;
      *(f32x4*)oc = *(const f32x4*)&sh.s.nr[t][j4];
    }
    __threadfence();
    __syncthreads();
    if (tid == 0) atomicExch(&g_cflag[b], 1);
  } else {
    // ---------------- C_seq forward-fill (4 blocks/batch, 64 c's each) ----
    const int blk2 = blk - 64;
    const int b = blk2 >> 2, cbase = (blk2 & 3) * 64;
    if (tid < L) sh.f.cb[tid] = c_seq[b * L + tid];
    if (tid == 0) {
      while (atomicAdd(&g_cflag[b], 0) == 0) __builtin_amdgcn_s_sleep(32);
    }
    __syncthreads();
    __threadfence();
    // phase A: stage this block's update rows
    if (tid < L) {
      const int c = sh.f.cb[tid];
      if (c >= cbase && c < cbase + 64) {
        const float* src = out + C_OFF + ((size_t)b * L + tid) * (NUM_C * NUM_D) + (size_t)c * NUM_D;
#pragma unroll
        for (int j = 0; j < 8; ++j)
          *(f32x4*)&sh.f.stage[tid][j * 4] = *(const f32x4*)(src + j * 4);
      }
    }
    __syncthreads();
    // phase B: pure store loop (each thread owns 8 floats of one c-row)
    const int cl = tid >> 2, dq = (tid & 3) * 8;
    const int myc = cbase + cl;
    float* base = out + C_OFF + (size_t)b * L * (NUM_C * NUM_D) + (size_t)myc * NUM_D + dq;
    f32x4 cur0 = (f32x4)0.0f, cur1 = (f32x4)0.0f;
    for (int t = 0; t < L; ++t) {
      if (sh.f.cb[t] == myc) {
        cur0 = *(const f32x4*)&sh.f.stage[t][dq];
        cur1 = *(const f32x4*)&sh.f.stage[t][dq + 4];
      }
      *(f32x4*)base = cur0;
      *(f32x4*)(base + 4) = cur1;
      base += NUM_C * NUM_D;
    }
    // ---------------- then: one 64-row alpha tile (blocks 64..163) --------
    const int job = blk - 64;           // 0..99 valid; 100..127 exit
    if (job >= 100) return;
    if (tid == 0) {
      while (atomicAdd(&g_gcnt, 0) < 32) __builtin_amdgcn_s_sleep(32);
    }
    __syncthreads();                    // also separates sh.f use from sh.a
    __threadfence();
    {
      const int r0 = tid >> 2, kc = (tid & 3) * 32;
      cvt32(out + H_OFF + (size_t)(job * 64 + r0) * V + kc, &sh.a.hls[r0][kc]);
    }
    __syncthreads();
    f32x4 acc1[8];
#pragma unroll
    for (int i = 0; i < 8; ++i) acc1[i] = (f32x4)0.0f;
#pragma unroll
    for (int c = 0; c < 4; ++c) {
      const short8 af = *(const short8*)&sh.a.hls[w * 16 + m][32 * c + 8 * q];
#pragma unroll
      for (int i = 0; i < 8; ++i) {
        const short8 bf = ldfrag(W1a + (size_t)(i * 16 + m) * V + 32 * c + 8 * q);
        acc1[i] = __builtin_amdgcn_mfma_f32_16x16x32_bf16(af, bf, acc1[i], 0, 0, 0);
      }
    }
#pragma unroll
    for (int i = 0; i < 8; ++i) {
      const int col = i * 16 + m;
      const float bias = b1a[col];
#pragma unroll
      for (int r = 0; r < 4; ++r)
        sh.a.hid[w * 16 + q * 4 + r][col] = f2bf(fmaxf(acc1[i][r] + bias, 0.f));
    }
    __syncthreads();
    f32x4 acc2[2];
    acc2[0] = (f32x4)0.0f; acc2[1] = (f32x4)0.0f;
#pragma unroll
    for (int c = 0; c < 4; ++c) {
      const short8 af = *(const short8*)&sh.a.hid[w * 16 + m][32 * c + 8 * q];
#pragma unroll
      for (int tt = 0; tt < 2; ++tt) {
        const short8 bf = ldfrag(W1b + (size_t)(tt * 16 + m) * V + 32 * c + 8 * q);
        acc2[tt] = __builtin_amdgcn_mfma_f32_16x16x32_bf16(af, bf, acc2[tt], 0, 0, 0);
      }
    }
#pragma unroll
    for (int tt = 0; tt < 2; ++tt) {
      const int col = tt * 16 + m;
      const float bias = b1b[col];
#pragma unroll
      for (int r = 0; r < 4; ++r) {
        const int row = job * 64 + w * 16 + q * 4 + r;
        out[ALPHA_OFF + (size_t)row * NUM_D + col] = acc2[tt][r] + bias;
      }
    }
  }
}

extern "C" void kernel_launch(void* const* d_in, const int* in_sizes, int n_in,
                              void* d_out, int out_size, void* d_ws, size_t ws_size,
                              hipStream_t stream) {
  const int*   c_seq  = (const int*)d_in[0];
  const int*   d_seq  = (const int*)d_in[1];
  const float* r_seq  = (const float*)d_in[2];
  const float* X      = (const float*)d_in[3];
  const float* v_r    = (const float*)d_in[4];
  const float* v_beta = (const float*)d_in[5];
  const float* W_ih   = (const float*)d_in[6];
  const float* W_hh   = (const float*)d_in[7];
  const float* b_ih   = (const float*)d_in[8];
  const float* b_hh   = (const float*)d_in[9];
  const float* W1a    = (const float*)d_in[10];
  const float* b1a    = (const float*)d_in[11];
  const float* W1b    = (const float*)d_in[12];
  const float* b1b    = (const float*)d_in[13];
  const float* W2a    = (const float*)d_in[14];
  const float* b2a    = (const float*)d_in[15];
  const float* W2b    = (const float*)d_in[16];
  const float* b2b    = (const float*)d_in[17];
  float* out = (float*)d_out;
  float* Q = (float*)d_ws;

  k1<<<dim3(100, 8), 256, 0, stream>>>(c_seq, d_seq, r_seq, X, v_r, W_ih, W2a, b_ih, b2a, Q);
  k23<<<192, 256, 0, stream>>>(c_seq, d_seq, W_hh, b_hh, W2a, v_beta, W2b, b2b,
                               W1a, b1a, W1b, b1b, Q, out);
}

// Round 13
// 379.394 us; speedup vs baseline: 1.0908x; 1.0106x over previous
//
#include <hip/hip_runtime.h>
#include <hip/hip_bf16.h>

typedef unsigned short u16;
typedef unsigned int u32;
typedef short short8 __attribute__((ext_vector_type(8)));
typedef float f32x4 __attribute__((ext_vector_type(4)));

constexpr int BATCH = 32, L = 200, NUM_C = 256, NUM_D = 32, V = 128;
constexpr int G3 = 384;                 // 3*V
constexpr int KQ = 512;                 // Q row: 384 gx | 128 P
constexpr int ROWS = BATCH * L;         // 6400
constexpr int TP = 208;                 // padded t (13 tiles x 16)
constexpr size_t ALPHA_OFF = 0;
constexpr size_t H_OFF = (size_t)ROWS * NUM_D;        // 204800
constexpr size_t C_OFF = H_OFF + (size_t)ROWS * V;    // 1024000

// cross-block pipeline flags (zeroed by k1 each launch; k1 precedes in-stream)
__device__ int g_gcnt;        // GRU blocks finished
__device__ int g_cflag[32];   // per-batch: scan block done

__device__ inline u16 f2bf(float f) {
  __hip_bfloat16 h = __float2bfloat16(f);
  return __builtin_bit_cast(u16, h);
}
__device__ inline float bf2f(u16 u) { u32 x = ((u32)u) << 16; return __builtin_bit_cast(float, x); }

// convert 32 contiguous f32 -> 32 bf16 (dst 8B-aligned)
__device__ inline void cvt32(const float* __restrict__ src, u16* __restrict__ dst) {
#pragma unroll
  for (int j0 = 0; j0 < 32; j0 += 4) {
    const f32x4 v = *(const f32x4*)(src + j0);
    ushort4 s;
    s.x = f2bf(v[0]); s.y = f2bf(v[1]); s.z = f2bf(v[2]); s.w = f2bf(v[3]);
    *(ushort4*)(dst + j0) = s;
  }
}
// load 8 contiguous f32 -> bf16 MFMA fragment
__device__ inline short8 ldfrag(const float* __restrict__ p) {
  const f32x4 a = *(const f32x4*)p, b = *(const f32x4*)(p + 4);
  short8 s;
  s[0] = (short)f2bf(a[0]); s[1] = (short)f2bf(a[1]);
  s[2] = (short)f2bf(a[2]); s[3] = (short)f2bf(a[3]);
  s[4] = (short)f2bf(b[0]); s[5] = (short)f2bf(b[1]);
  s[6] = (short)f2bf(b[2]); s[7] = (short)f2bf(b[3]);
  return s;
}

// ---------------------------------------------------------------------------
// K1: Q[row, 0:384] = gru_in @ W_ih^T + b_ih ; Q[row, 384:512] = P (mem MLP)
//     (also zeroes the k23 pipeline flags)
// ---------------------------------------------------------------------------
__global__ __launch_bounds__(256) void k1(
    const int* __restrict__ c_seq, const int* __restrict__ d_seq,
    const float* __restrict__ r_seq, const float* __restrict__ X,
    const float* __restrict__ v_r, const float* __restrict__ W_ih,
    const float* __restrict__ W2a, const float* __restrict__ b_ih,
    const float* __restrict__ b2a, float* __restrict__ Qout)
{
  __shared__ __align__(16) u16 Als[64][144];
  __shared__ __align__(16) u16 Bls[64][144];
  const int tid = threadIdx.x;
  if (blockIdx.x == 0 && blockIdx.y == 0 && tid == 0) {
    g_gcnt = 0;
#pragma unroll
    for (int i = 0; i < 32; ++i) g_cflag[i] = 0;
  }
  const int mt = blockIdx.x, nt = blockIdx.y;
  const int lane = tid & 63, w = tid >> 6;
  const int q = lane >> 4, m = lane & 15;

  f32x4 acc[4];
#pragma unroll
  for (int i = 0; i < 4; ++i) acc[i] = (f32x4)0.0f;

  const int r0 = tid >> 2;          // 0..63 staged row
  const int kc = (tid & 3) * 32;    // k chunk
  const int rowg = mt * 64 + r0;    // global (b,t) row
  const int gcolB = nt * 64 + r0;   // global output col staged as B row

  for (int s = 0; s < 2; ++s) {     // two K-stages of 128
    if (s) __syncthreads();
    if (s == 0) {
      const int idx = c_seq[rowg] + NUM_C * d_seq[rowg];
      cvt32(X + (size_t)idx * V + kc, &Als[r0][kc]);
    } else {
      const float rv = r_seq[rowg];
#pragma unroll
      for (int j0 = 0; j0 < 32; j0 += 4) {
        const f32x4 v = *(const f32x4*)(v_r + kc + j0);
        ushort4 sv;
        sv.x = f2bf(rv * v[0]); sv.y = f2bf(rv * v[1]);
        sv.z = f2bf(rv * v[2]); sv.w = f2bf(rv * v[3]);
        *(ushort4*)&Als[r0][kc + j0] = sv;
      }
    }
    {
      const float* src = (gcolB < G3)
        ? (W_ih + (size_t)gcolB * 256 + s * 128 + kc)
        : (W2a + (size_t)(gcolB - G3) * G3 + V + s * 128 + kc);
      cvt32(src, &Bls[r0][kc]);
    }
    __syncthreads();
#pragma unroll
    for (int c = 0; c < 4; ++c) {
      const short8 af = *(const short8*)&Als[w * 16 + m][32 * c + 8 * q];
#pragma unroll
      for (int i = 0; i < 4; ++i) {
        const short8 bf = *(const short8*)&Bls[i * 16 + m][32 * c + 8 * q];
        acc[i] = __builtin_amdgcn_mfma_f32_16x16x32_bf16(af, bf, acc[i], 0, 0, 0);
      }
    }
  }
#pragma unroll
  for (int i = 0; i < 4; ++i) {
    const int col = nt * 64 + i * 16 + m;
    const float bias = (col < G3) ? b_ih[col] : b2a[col - G3];
#pragma unroll
    for (int r = 0; r < 4; ++r) {
      const int rowo = mt * 64 + w * 16 + q * 4 + r;
      Qout[(size_t)rowo * KQ + col] = acc[i][r] + bias;
    }
  }
}

// ---------------------------------------------------------------------------
// K23 (fused, flag-pipelined) — PRIVATE-CU layout (LDS>80KB -> 1 block/CU;
// 192 blocks <= 256 CUs -> all resident by capacity, spin-wait safe):
//   blocks   0.. 31: GRU batch b -> g_gcnt++.  NEW vs r12: h is buffered in
//                    LDS (hbuf[200][128] f32, 102KB) and flushed ONCE after
//                    the loop. The 200-step loop now has ZERO global stores,
//                    so its vmcnt waits track only the 6 gx loads — the
//                    serial chain is decoupled from the fill blocks' 210MB
//                    store-queue congestion (stores+loads share vmcnt).
//   blocks  32.. 63: memory-scan parallel fixpoint -> g_cflag[b]=1
//   blocks  64..191: C_seq forward-fill (4/batch), waits g_cflag[b];
//                    blocks 64..163 then run ONE 64-row alpha tile after
//                    waiting g_gcnt==32.
// ---------------------------------------------------------------------------
union ShK23 {
  struct { u16 h_bf[2][V]; float hbuf[L][V]; } g;   // 0.5KB + 102.4KB
  struct {
    int cb[TP]; int db[TP]; int sp[TP];
    float nr[TP][36];                 // n(t) rows; stride 36 (16B-aligned)
    float u[V];
    int maxd;
  } s;
  struct { int cb[L]; float stage[L][NUM_D]; } f;
  struct { u16 hls[64][144]; u16 hid[64][144]; } a;
  struct { char p[84000]; } pad;      // floor: keeps 1 block/CU even if g shrinks
};

__global__ __launch_bounds__(256, 1) void k23(
    const int* __restrict__ c_seq, const int* __restrict__ d_seq,
    const float* __restrict__ W_hh, const float* __restrict__ b_hh,
    const float* __restrict__ W2a, const float* __restrict__ v_beta,
    const float* __restrict__ W2b, const float* __restrict__ b2b,
    const float* __restrict__ W1a, const float* __restrict__ b1a,
    const float* __restrict__ W1b, const float* __restrict__ b1b,
    const float* __restrict__ Q, float* __restrict__ out)
{
  __shared__ __align__(16) ShK23 sh;
  const int tid = threadIdx.x;
  const int l = tid & 63, w = tid >> 6, q = l >> 4, m = l & 15;
  const int blk = blockIdx.x;

  if (blk < 32) {
    // ---------------- GRU (r10 loop, h-stores moved to LDS) ---------------
    const int b = blk;
    if (tid < V) sh.g.h_bf[0][tid] = 0;
    __syncthreads();
    short8 wf[6][4];
    float bhh[6]; int gcol[6];
#pragma unroll
    for (int i = 0; i < 6; ++i) {
      const int g = (w + 4 * i) * 16 + m;
      gcol[i] = g;
      bhh[i] = b_hh[g];
#pragma unroll
      for (int c = 0; c < 4; ++c)
        wf[i][c] = ldfrag(W_hh + (size_t)g * V + 32 * c + 8 * q);
    }
    const float* Qb = Q + (size_t)b * L * KQ;
    float* outh = out + H_OFF + (size_t)b * L * V;
    const int vi0 = 16 * w + m, vi1 = 64 + 16 * w + m;
    float hold[2] = {0.f, 0.f};
    const f32x4 z4 = (f32x4)0.0f;
    float gxA[6], gxB[6];
#pragma unroll
    for (int i = 0; i < 6; ++i) gxA[i] = Qb[gcol[i]];
#pragma unroll
    for (int i = 0; i < 6; ++i) gxB[i] = Qb[KQ + gcol[i]];

    auto step = [&](int t, float (&gx)[6]) {
      const int rs = t & 1, wsl = rs ^ 1;
      short8 af[4];
#pragma unroll
      for (int c = 0; c < 4; ++c)
        af[c] = *(const short8*)&sh.g.h_bf[rs][32 * c + 8 * q];
      f32x4 acc[6];
#pragma unroll
      for (int i = 0; i < 6; ++i)
        acc[i] = __builtin_amdgcn_mfma_f32_16x16x32_bf16(af[0], wf[i][0], z4, 0, 0, 0);
#pragma unroll
      for (int c = 1; c < 4; ++c)
#pragma unroll
        for (int i = 0; i < 6; ++i)
          acc[i] = __builtin_amdgcn_mfma_f32_16x16x32_bf16(af[c], wf[i][c], acc[i], 0, 0, 0);
      float hnew[2];
#pragma unroll
      for (int s = 0; s < 2; ++s) {
        const float xr = gx[0 + s] + acc[0 + s][0] + bhh[0 + s];
        const float xz = gx[2 + s] + acc[2 + s][0] + bhh[2 + s];
        const float ghn = acc[4 + s][0] + bhh[4 + s];
        const float r = 1.f / (1.f + __expf(-xr));
        const float z = 1.f / (1.f + __expf(-xz));
        const float xn = gx[4 + s] + r * ghn;
        const float e = __expf(2.f * xn);
        const float n = 1.f - 2.f / (e + 1.f);     // tanh(xn)
        hnew[s] = (1.f - z) * n + z * hold[s];
      }
      if (q == 0) {
        sh.g.h_bf[wsl][vi0] = f2bf(hnew[0]);
        sh.g.h_bf[wsl][vi1] = f2bf(hnew[1]);
        sh.g.hbuf[t][vi0] = hnew[0];      // LDS h buffer (no global store!)
        sh.g.hbuf[t][vi1] = hnew[1];
      }
      hold[0] = hnew[0]; hold[1] = hnew[1];
      if (t + 2 < L) {
        const float* Qr = Qb + (size_t)(t + 2) * KQ;
#pragma unroll
        for (int i = 0; i < 6; ++i) gx[i] = Qr[gcol[i]];
      }
      __builtin_amdgcn_s_waitcnt(0xc07f);   // lgkmcnt(0)
      __builtin_amdgcn_s_barrier();
    };

    for (int t = 0; t < L; t += 2) {
      step(t, gxA);
      step(t + 1, gxB);
    }
    // flush h buffer -> global (coalesced, one burst, ~102KB)
    {
      const f32x4* src = (const f32x4*)&sh.g.hbuf[0][0];
      f32x4* dst = (f32x4*)outh;
      for (int i = tid; i < L * V / 4; i += 256) dst[i] = src[i];
    }
    __threadfence();
    __syncthreads();
    if (tid == 0) atomicAdd(&g_gcnt, 1);
  } else if (blk < 64) {
    // ---------------- memory scan: parallel fixpoint (round-8) ------------
    const int b = blk - 32;
    for (int i = tid; i < TP; i += 256) {
      int c = -1, d = 0;
      if (i < L) { c = c_seq[b * L + i]; d = d_seq[b * L + i]; }
      sh.s.cb[i] = c; sh.s.db[i] = d; sh.s.sp[i] = -1;
    }
    if (tid < V) {
      float a = 0.f;
      const float* wr = W2a + (size_t)tid * G3;
      for (int k = 0; k < V; ++k) a += wr[k] * v_beta[k];
      sh.s.u[tid] = a;
    }
    if (tid == 0) sh.s.maxd = 0;
    __syncthreads();
    {
      const int c = tid;               // 256 threads == NUM_C
      int prev = -1;
      for (int t4 = 0; t4 < L; t4 += 4) {
        const int4 v = *(const int4*)&sh.s.cb[t4];
        if (v.x == c) { sh.s.sp[t4 + 0] = prev; prev = t4 + 0; }
        if (v.y == c) { sh.s.sp[t4 + 1] = prev; prev = t4 + 1; }
        if (v.z == c) { sh.s.sp[t4 + 2] = prev; prev = t4 + 2; }
        if (v.w == c) { sh.s.sp[t4 + 3] = prev; prev = t4 + 3; }
      }
    }
    __syncthreads();
    {
      int dmx = 0;
      for (int t = tid; t < L; t += 256) {
        int dd = 0, s = sh.s.sp[t];
        while (s >= 0) { ++dd; s = sh.s.sp[s]; }
        dmx = dmx > dd ? dmx : dd;
      }
      atomicMax(&sh.s.maxd, dmx);
    }
    __syncthreads();
    const int rounds = sh.s.maxd + 1;
    float ureg[4][8];
#pragma unroll
    for (int c = 0; c < 4; ++c)
#pragma unroll
      for (int j = 0; j < 8; ++j) ureg[c][j] = sh.s.u[32 * c + 8 * q + j];
    short8 wbf[2][4];
    float bb[2];
#pragma unroll
    for (int tt = 0; tt < 2; ++tt) {
#pragma unroll
      for (int c = 0; c < 4; ++c)
        wbf[tt][c] = ldfrag(W2b + (size_t)(tt * 16 + m) * V + 32 * c + 8 * q);
      bb[tt] = b2b[tt * 16 + m];
    }
    const f32x4 z4 = (f32x4)0.0f;
    for (int rd = 0; rd < rounds; ++rd) {
      for (int ti = w; ti < 13; ti += 4) {
        const int t0 = ti * 16;
        const int tt = t0 + m;
        const bool ok = tt < L;
        const int spv = ok ? sh.s.sp[tt] : -1;
        const int dbv = ok ? sh.s.db[tt] : 0;
        const float beta = (spv >= 0) ? sh.s.nr[spv][dbv] : 0.f;
        const float* pr = Q + ((size_t)b * L + tt) * KQ + G3 + 8 * q;
        short8 af[4];
#pragma unroll
        for (int c = 0; c < 4; ++c) {
          const f32x4 p0 = ok ? *(const f32x4*)(pr + 32 * c) : (f32x4)0.0f;
          const f32x4 p1 = ok ? *(const f32x4*)(pr + 32 * c + 4) : (f32x4)0.0f;
          short8 a;
#pragma unroll
          for (int j = 0; j < 8; ++j) {
            const float pv = (j < 4) ? p0[j] : p1[j - 4];
            a[j] = (short)f2bf(fmaxf(beta * ureg[c][j] + pv, 0.f));
          }
          af[c] = a;
        }
        f32x4 a0 = z4, a1 = z4;
#pragma unroll
        for (int c = 0; c < 4; ++c) {
          a0 = __builtin_amdgcn_mfma_f32_16x16x32_bf16(af[c], wbf[0][c], a0, 0, 0, 0);
          a1 = __builtin_amdgcn_mfma_f32_16x16x32_bf16(af[c], wbf[1][c], a1, 0, 0, 0);
        }
#pragma unroll
        for (int r = 0; r < 4; ++r) {
          const int tr = t0 + q * 4 + r;
          sh.s.nr[tr][m]      = a0[r] + bb[0];
          sh.s.nr[tr][16 + m] = a1[r] + bb[1];
        }
      }
      __syncthreads();
    }
    float* outc = out + C_OFF + (size_t)b * L * (NUM_C * NUM_D);
    const int j4 = (tid & 7) * 4;
    for (int t = tid >> 3; t < L; t += 32) {
      const int c = sh.s.cb[t];
      float* oc = outc + (size_t)t * (NUM_C * NUM_D) + c * NUM_D + j4;
      *(f32x4*)oc = *(const f32x4*)&sh.s.nr[t][j4];
    }
    __threadfence();
    __syncthreads();
    if (tid == 0) atomicExch(&g_cflag[b], 1);
  } else {
    // ---------------- C_seq forward-fill (4 blocks/batch, 64 c's each) ----
    const int blk2 = blk - 64;
    const int b = blk2 >> 2, cbase = (blk2 & 3) * 64;
    if (tid < L) sh.f.cb[tid] = c_seq[b * L + tid];
    if (tid == 0) {
      while (atomicAdd(&g_cflag[b], 0) == 0) __builtin_amdgcn_s_sleep(32);
    }
    __syncthreads();
    __threadfence();
    // phase A: stage this block's update rows
    if (tid < L) {
      const int c = sh.f.cb[tid];
      if (c >= cbase && c < cbase + 64) {
        const float* src = out + C_OFF + ((size_t)b * L + tid) * (NUM_C * NUM_D) + (size_t)c * NUM_D;
#pragma unroll
        for (int j = 0; j < 8; ++j)
          *(f32x4*)&sh.f.stage[tid][j * 4] = *(const f32x4*)(src + j * 4);
      }
    }
    __syncthreads();
    // phase B: pure store loop (each thread owns 8 floats of one c-row)
    const int cl = tid >> 2, dq = (tid & 3) * 8;
    const int myc = cbase + cl;
    float* base = out + C_OFF + (size_t)b * L * (NUM_C * NUM_D) + (size_t)myc * NUM_D + dq;
    f32x4 cur0 = (f32x4)0.0f, cur1 = (f32x4)0.0f;
    for (int t = 0; t < L; ++t) {
      if (sh.f.cb[t] == myc) {
        cur0 = *(const f32x4*)&sh.f.stage[t][dq];
        cur1 = *(const f32x4*)&sh.f.stage[t][dq + 4];
      }
      *(f32x4*)base = cur0;
      *(f32x4*)(base + 4) = cur1;
      base += NUM_C * NUM_D;
    }
    // ---------------- then: one 64-row alpha tile (blocks 64..163) --------
    const int job = blk - 64;           // 0..99 valid; 100..127 exit
    if (job >= 100) return;
    if (tid == 0) {
      while (atomicAdd(&g_gcnt, 0) < 32) __builtin_amdgcn_s_sleep(32);
    }
    __syncthreads();                    // also separates sh.f use from sh.a
    __threadfence();
    {
      const int r0 = tid >> 2, kc = (tid & 3) * 32;
      cvt32(out + H_OFF + (size_t)(job * 64 + r0) * V + kc, &sh.a.hls[r0][kc]);
    }
    __syncthreads();
    f32x4 acc1[8];
#pragma unroll
    for (int i = 0; i < 8; ++i) acc1[i] = (f32x4)0.0f;
#pragma unroll
    for (int c = 0; c < 4; ++c) {
      const short8 af = *(const short8*)&sh.a.hls[w * 16 + m][32 * c + 8 * q];
#pragma unroll
      for (int i = 0; i < 8; ++i) {
        const short8 bf = ldfrag(W1a + (size_t)(i * 16 + m) * V + 32 * c + 8 * q);
        acc1[i] = __builtin_amdgcn_mfma_f32_16x16x32_bf16(af, bf, acc1[i], 0, 0, 0);
      }
    }
#pragma unroll
    for (int i = 0; i < 8; ++i) {
      const int col = i * 16 + m;
      const float bias = b1a[col];
#pragma unroll
      for (int r = 0; r < 4; ++r)
        sh.a.hid[w * 16 + q * 4 + r][col] = f2bf(fmaxf(acc1[i][r] + bias, 0.f));
    }
    __syncthreads();
    f32x4 acc2[2];
    acc2[0] = (f32x4)0.0f; acc2[1] = (f32x4)0.0f;
#pragma unroll
    for (int c = 0; c < 4; ++c) {
      const short8 af = *(const short8*)&sh.a.hid[w * 16 + m][32 * c + 8 * q];
#pragma unroll
      for (int tt = 0; tt < 2; ++tt) {
        const short8 bf = ldfrag(W1b + (size_t)(tt * 16 + m) * V + 32 * c + 8 * q);
        acc2[tt] = __builtin_amdgcn_mfma_f32_16x16x32_bf16(af, bf, acc2[tt], 0, 0, 0);
      }
    }
#pragma unroll
    for (int tt = 0; tt < 2; ++tt) {
      const int col = tt * 16 + m;
      const float bias = b1b[col];
#pragma unroll
      for (int r = 0; r < 4; ++r) {
        const int row = job * 64 + w * 16 + q * 4 + r;
        out[ALPHA_OFF + (size_t)row * NUM_D + col] = acc2[tt][r] + bias;
      }
    }
  }
}

extern "C" void kernel_launch(void* const* d_in, const int* in_sizes, int n_in,
                              void* d_out, int out_size, void* d_ws, size_t ws_size,
                              hipStream_t stream) {
  const int*   c_seq  = (const int*)d_in[0];
  const int*   d_seq  = (const int*)d_in[1];
  const float* r_seq  = (const float*)d_in[2];
  const float* X      = (const float*)d_in[3];
  const float* v_r    = (const float*)d_in[4];
  const float* v_beta = (const float*)d_in[5];
  const float* W_ih   = (const float*)d_in[6];
  const float* W_hh   = (const float*)d_in[7];
  const float* b_ih   = (const float*)d_in[8];
  const float* b_hh   = (const float*)d_in[9];
  const float* W1a    = (const float*)d_in[10];
  const float* b1a    = (const float*)d_in[11];
  const float* W1b    = (const float*)d_in[12];
  const float* b1b    = (const float*)d_in[13];
  const float* W2a    = (const float*)d_in[14];
  const float* b2a    = (const float*)d_in[15];
  const float* W2b    = (const float*)d_in[16];
  const float* b2b    = (const float*)d_in[17];
  float* out = (float*)d_out;
  float* Q = (float*)d_ws;

  k1<<<dim3(100, 8), 256, 0, stream>>>(c_seq, d_seq, r_seq, X, v_r, W_ih, W2a, b_ih, b2a, Q);
  k23<<<192, 256, 0, stream>>>(c_seq, d_seq, W_hh, b_hh, W2a, v_beta, W2b, b2b,
                               W1a, b1a, W1b, b1b, Q, out);
}

// Round 14
// 371.588 us; speedup vs baseline: 1.1137x; 1.0210x over previous
//
#include <hip/hip_runtime.h>
#include <hip/hip_bf16.h>

typedef unsigned short u16;
typedef unsigned int u32;
typedef short short8 __attribute__((ext_vector_type(8)));
typedef float f32x4 __attribute__((ext_vector_type(4)));

constexpr int BATCH = 32, L = 200, NUM_C = 256, NUM_D = 32, V = 128;
constexpr int G3 = 384;                 // 3*V
constexpr int KQ = 512;                 // Q row: 384 gx | 128 P
constexpr int ROWS = BATCH * L;         // 6400
constexpr int TP = 208;                 // padded t (13 tiles x 16)
constexpr size_t ALPHA_OFF = 0;
constexpr size_t H_OFF = (size_t)ROWS * NUM_D;        // 204800
constexpr size_t C_OFF = H_OFF + (size_t)ROWS * V;    // 1024000

// cross-block pipeline flags (zeroed by k1 each launch; k1 precedes in-stream)
__device__ int g_gcnt;        // GRU blocks finished
__device__ int g_cflag[32];   // per-batch: scan block done

__device__ inline u16 f2bf(float f) {
  __hip_bfloat16 h = __float2bfloat16(f);
  return __builtin_bit_cast(u16, h);
}
__device__ inline float bf2f(u16 u) { u32 x = ((u32)u) << 16; return __builtin_bit_cast(float, x); }

// convert 32 contiguous f32 -> 32 bf16 (dst 8B-aligned)
__device__ inline void cvt32(const float* __restrict__ src, u16* __restrict__ dst) {
#pragma unroll
  for (int j0 = 0; j0 < 32; j0 += 4) {
    const f32x4 v = *(const f32x4*)(src + j0);
    ushort4 s;
    s.x = f2bf(v[0]); s.y = f2bf(v[1]); s.z = f2bf(v[2]); s.w = f2bf(v[3]);
    *(ushort4*)(dst + j0) = s;
  }
}
// load 8 contiguous f32 -> bf16 MFMA fragment
__device__ inline short8 ldfrag(const float* __restrict__ p) {
  const f32x4 a = *(const f32x4*)p, b = *(const f32x4*)(p + 4);
  short8 s;
  s[0] = (short)f2bf(a[0]); s[1] = (short)f2bf(a[1]);
  s[2] = (short)f2bf(a[2]); s[3] = (short)f2bf(a[3]);
  s[4] = (short)f2bf(b[0]); s[5] = (short)f2bf(b[1]);
  s[6] = (short)f2bf(b[2]); s[7] = (short)f2bf(b[3]);
  return s;
}

// ---------------------------------------------------------------------------
// K1: Q[row, 0:384] = gru_in @ W_ih^T + b_ih ; Q[row, 384:512] = P (mem MLP)
//     (also zeroes the k23 pipeline flags)
// ---------------------------------------------------------------------------
__global__ __launch_bounds__(256) void k1(
    const int* __restrict__ c_seq, const int* __restrict__ d_seq,
    const float* __restrict__ r_seq, const float* __restrict__ X,
    const float* __restrict__ v_r, const float* __restrict__ W_ih,
    const float* __restrict__ W2a, const float* __restrict__ b_ih,
    const float* __restrict__ b2a, float* __restrict__ Qout)
{
  __shared__ __align__(16) u16 Als[64][144];
  __shared__ __align__(16) u16 Bls[64][144];
  const int tid = threadIdx.x;
  if (blockIdx.x == 0 && blockIdx.y == 0 && tid == 0) {
    g_gcnt = 0;
#pragma unroll
    for (int i = 0; i < 32; ++i) g_cflag[i] = 0;
  }
  const int mt = blockIdx.x, nt = blockIdx.y;
  const int lane = tid & 63, w = tid >> 6;
  const int q = lane >> 4, m = lane & 15;

  f32x4 acc[4];
#pragma unroll
  for (int i = 0; i < 4; ++i) acc[i] = (f32x4)0.0f;

  const int r0 = tid >> 2;          // 0..63 staged row
  const int kc = (tid & 3) * 32;    // k chunk
  const int rowg = mt * 64 + r0;    // global (b,t) row
  const int gcolB = nt * 64 + r0;   // global output col staged as B row

  for (int s = 0; s < 2; ++s) {     // two K-stages of 128
    if (s) __syncthreads();
    if (s == 0) {
      const int idx = c_seq[rowg] + NUM_C * d_seq[rowg];
      cvt32(X + (size_t)idx * V + kc, &Als[r0][kc]);
    } else {
      const float rv = r_seq[rowg];
#pragma unroll
      for (int j0 = 0; j0 < 32; j0 += 4) {
        const f32x4 v = *(const f32x4*)(v_r + kc + j0);
        ushort4 sv;
        sv.x = f2bf(rv * v[0]); sv.y = f2bf(rv * v[1]);
        sv.z = f2bf(rv * v[2]); sv.w = f2bf(rv * v[3]);
        *(ushort4*)&Als[r0][kc + j0] = sv;
      }
    }
    {
      const float* src = (gcolB < G3)
        ? (W_ih + (size_t)gcolB * 256 + s * 128 + kc)
        : (W2a + (size_t)(gcolB - G3) * G3 + V + s * 128 + kc);
      cvt32(src, &Bls[r0][kc]);
    }
    __syncthreads();
#pragma unroll
    for (int c = 0; c < 4; ++c) {
      const short8 af = *(const short8*)&Als[w * 16 + m][32 * c + 8 * q];
#pragma unroll
      for (int i = 0; i < 4; ++i) {
        const short8 bf = *(const short8*)&Bls[i * 16 + m][32 * c + 8 * q];
        acc[i] = __builtin_amdgcn_mfma_f32_16x16x32_bf16(af, bf, acc[i], 0, 0, 0);
      }
    }
  }
#pragma unroll
  for (int i = 0; i < 4; ++i) {
    const int col = nt * 64 + i * 16 + m;
    const float bias = (col < G3) ? b_ih[col] : b2a[col - G3];
#pragma unroll
    for (int r = 0; r < 4; ++r) {
      const int rowo = mt * 64 + w * 16 + q * 4 + r;
      Qout[(size_t)rowo * KQ + col] = acc[i][r] + bias;
    }
  }
}

// ---------------------------------------------------------------------------
// K23 (fused, flag-pipelined) — PRIVATE-CU layout (LDS>80KB -> 1 block/CU;
// 192 blocks <= 256 CUs -> all resident by capacity, spin-wait safe):
//   blocks   0.. 31: GRU batch b -> g_gcnt++.  h buffered in LDS (hbuf,
//                    102KB), flushed once after the loop (r13). NEW vs r13:
//                    DEPTH-4 gx register prefetch (banks A..D, unroll-4,
//                    bank t reloads row t+4) — ~4 step-bodies of slack vs
//                    congestion-inflated load latency during the fill burst.
//   blocks  32.. 63: memory-scan parallel fixpoint -> g_cflag[b]=1
//   blocks  64..191: C_seq forward-fill (4/batch), waits g_cflag[b];
//                    blocks 64..163 then run ONE 64-row alpha tile after
//                    waiting g_gcnt==32.
// ---------------------------------------------------------------------------
union ShK23 {
  struct { u16 h_bf[2][V]; float hbuf[L][V]; } g;   // 0.5KB + 102.4KB
  struct {
    int cb[TP]; int db[TP]; int sp[TP];
    float nr[TP][36];                 // n(t) rows; stride 36 (16B-aligned)
    float u[V];
    int maxd;
  } s;
  struct { int cb[L]; float stage[L][NUM_D]; } f;
  struct { u16 hls[64][144]; u16 hid[64][144]; } a;
  struct { char p[84000]; } pad;      // floor: keeps 1 block/CU even if g shrinks
};

__global__ __launch_bounds__(256, 1) void k23(
    const int* __restrict__ c_seq, const int* __restrict__ d_seq,
    const float* __restrict__ W_hh, const float* __restrict__ b_hh,
    const float* __restrict__ W2a, const float* __restrict__ v_beta,
    const float* __restrict__ W2b, const float* __restrict__ b2b,
    const float* __restrict__ W1a, const float* __restrict__ b1a,
    const float* __restrict__ W1b, const float* __restrict__ b1b,
    const float* __restrict__ Q, float* __restrict__ out)
{
  __shared__ __align__(16) ShK23 sh;
  const int tid = threadIdx.x;
  const int l = tid & 63, w = tid >> 6, q = l >> 4, m = l & 15;
  const int blk = blockIdx.x;

  if (blk < 32) {
    // ---------------- GRU (r13 loop, depth-4 gx banks) --------------------
    const int b = blk;
    if (tid < V) sh.g.h_bf[0][tid] = 0;
    __syncthreads();
    short8 wf[6][4];
    float bhh[6]; int gcol[6];
#pragma unroll
    for (int i = 0; i < 6; ++i) {
      const int g = (w + 4 * i) * 16 + m;
      gcol[i] = g;
      bhh[i] = b_hh[g];
#pragma unroll
      for (int c = 0; c < 4; ++c)
        wf[i][c] = ldfrag(W_hh + (size_t)g * V + 32 * c + 8 * q);
    }
    const float* Qb = Q + (size_t)b * L * KQ;
    float* outh = out + H_OFF + (size_t)b * L * V;
    const int vi0 = 16 * w + m, vi1 = 64 + 16 * w + m;
    float hold[2] = {0.f, 0.f};
    const f32x4 z4 = (f32x4)0.0f;
    float gxA[6], gxB[6], gxC[6], gxD[6];
#pragma unroll
    for (int i = 0; i < 6; ++i) gxA[i] = Qb[gcol[i]];
#pragma unroll
    for (int i = 0; i < 6; ++i) gxB[i] = Qb[KQ + gcol[i]];
#pragma unroll
    for (int i = 0; i < 6; ++i) gxC[i] = Qb[2 * KQ + gcol[i]];
#pragma unroll
    for (int i = 0; i < 6; ++i) gxD[i] = Qb[3 * KQ + gcol[i]];

    auto step = [&](int t, float (&gx)[6]) {
      const int rs = t & 1, wsl = rs ^ 1;
      short8 af[4];
#pragma unroll
      for (int c = 0; c < 4; ++c)
        af[c] = *(const short8*)&sh.g.h_bf[rs][32 * c + 8 * q];
      f32x4 acc[6];
#pragma unroll
      for (int i = 0; i < 6; ++i)
        acc[i] = __builtin_amdgcn_mfma_f32_16x16x32_bf16(af[0], wf[i][0], z4, 0, 0, 0);
#pragma unroll
      for (int c = 1; c < 4; ++c)
#pragma unroll
        for (int i = 0; i < 6; ++i)
          acc[i] = __builtin_amdgcn_mfma_f32_16x16x32_bf16(af[c], wf[i][c], acc[i], 0, 0, 0);
      float hnew[2];
#pragma unroll
      for (int s = 0; s < 2; ++s) {
        const float xr = gx[0 + s] + acc[0 + s][0] + bhh[0 + s];
        const float xz = gx[2 + s] + acc[2 + s][0] + bhh[2 + s];
        const float ghn = acc[4 + s][0] + bhh[4 + s];
        const float r = 1.f / (1.f + __expf(-xr));
        const float z = 1.f / (1.f + __expf(-xz));
        const float xn = gx[4 + s] + r * ghn;
        const float e = __expf(2.f * xn);
        const float n = 1.f - 2.f / (e + 1.f);     // tanh(xn)
        hnew[s] = (1.f - z) * n + z * hold[s];
      }
      if (q == 0) {
        sh.g.h_bf[wsl][vi0] = f2bf(hnew[0]);
        sh.g.h_bf[wsl][vi1] = f2bf(hnew[1]);
        sh.g.hbuf[t][vi0] = hnew[0];      // LDS h buffer (no global store)
        sh.g.hbuf[t][vi1] = hnew[1];
      }
      hold[0] = hnew[0]; hold[1] = hnew[1];
      if (t + 4 < L) {                    // reload this bank for t+4
        const float* Qr = Qb + (size_t)(t + 4) * KQ;
#pragma unroll
        for (int i = 0; i < 6; ++i) gx[i] = Qr[gcol[i]];
      }
      __builtin_amdgcn_s_waitcnt(0xc07f);   // lgkmcnt(0)
      __builtin_amdgcn_s_barrier();
    };

    for (int t = 0; t < L; t += 4) {
      step(t, gxA);
      step(t + 1, gxB);
      step(t + 2, gxC);
      step(t + 3, gxD);
    }
    // flush h buffer -> global (coalesced, one burst, ~102KB)
    {
      const f32x4* src = (const f32x4*)&sh.g.hbuf[0][0];
      f32x4* dst = (f32x4*)outh;
      for (int i = tid; i < L * V / 4; i += 256) dst[i] = src[i];
    }
    __threadfence();
    __syncthreads();
    if (tid == 0) atomicAdd(&g_gcnt, 1);
  } else if (blk < 64) {
    // ---------------- memory scan: parallel fixpoint (round-8) ------------
    const int b = blk - 32;
    for (int i = tid; i < TP; i += 256) {
      int c = -1, d = 0;
      if (i < L) { c = c_seq[b * L + i]; d = d_seq[b * L + i]; }
      sh.s.cb[i] = c; sh.s.db[i] = d; sh.s.sp[i] = -1;
    }
    if (tid < V) {
      float a = 0.f;
      const float* wr = W2a + (size_t)tid * G3;
      for (int k = 0; k < V; ++k) a += wr[k] * v_beta[k];
      sh.s.u[tid] = a;
    }
    if (tid == 0) sh.s.maxd = 0;
    __syncthreads();
    {
      const int c = tid;               // 256 threads == NUM_C
      int prev = -1;
      for (int t4 = 0; t4 < L; t4 += 4) {
        const int4 v = *(const int4*)&sh.s.cb[t4];
        if (v.x == c) { sh.s.sp[t4 + 0] = prev; prev = t4 + 0; }
        if (v.y == c) { sh.s.sp[t4 + 1] = prev; prev = t4 + 1; }
        if (v.z == c) { sh.s.sp[t4 + 2] = prev; prev = t4 + 2; }
        if (v.w == c) { sh.s.sp[t4 + 3] = prev; prev = t4 + 3; }
      }
    }
    __syncthreads();
    {
      int dmx = 0;
      for (int t = tid; t < L; t += 256) {
        int dd = 0, s = sh.s.sp[t];
        while (s >= 0) { ++dd; s = sh.s.sp[s]; }
        dmx = dmx > dd ? dmx : dd;
      }
      atomicMax(&sh.s.maxd, dmx);
    }
    __syncthreads();
    const int rounds = sh.s.maxd + 1;
    float ureg[4][8];
#pragma unroll
    for (int c = 0; c < 4; ++c)
#pragma unroll
      for (int j = 0; j < 8; ++j) ureg[c][j] = sh.s.u[32 * c + 8 * q + j];
    short8 wbf[2][4];
    float bb[2];
#pragma unroll
    for (int tt = 0; tt < 2; ++tt) {
#pragma unroll
      for (int c = 0; c < 4; ++c)
        wbf[tt][c] = ldfrag(W2b + (size_t)(tt * 16 + m) * V + 32 * c + 8 * q);
      bb[tt] = b2b[tt * 16 + m];
    }
    const f32x4 z4 = (f32x4)0.0f;
    for (int rd = 0; rd < rounds; ++rd) {
      for (int ti = w; ti < 13; ti += 4) {
        const int t0 = ti * 16;
        const int tt = t0 + m;
        const bool ok = tt < L;
        const int spv = ok ? sh.s.sp[tt] : -1;
        const int dbv = ok ? sh.s.db[tt] : 0;
        const float beta = (spv >= 0) ? sh.s.nr[spv][dbv] : 0.f;
        const float* pr = Q + ((size_t)b * L + tt) * KQ + G3 + 8 * q;
        short8 af[4];
#pragma unroll
        for (int c = 0; c < 4; ++c) {
          const f32x4 p0 = ok ? *(const f32x4*)(pr + 32 * c) : (f32x4)0.0f;
          const f32x4 p1 = ok ? *(const f32x4*)(pr + 32 * c + 4) : (f32x4)0.0f;
          short8 a;
#pragma unroll
          for (int j = 0; j < 8; ++j) {
            const float pv = (j < 4) ? p0[j] : p1[j - 4];
            a[j] = (short)f2bf(fmaxf(beta * ureg[c][j] + pv, 0.f));
          }
          af[c] = a;
        }
        f32x4 a0 = z4, a1 = z4;
#pragma unroll
        for (int c = 0; c < 4; ++c) {
          a0 = __builtin_amdgcn_mfma_f32_16x16x32_bf16(af[c], wbf[0][c], a0, 0, 0, 0);
          a1 = __builtin_amdgcn_mfma_f32_16x16x32_bf16(af[c], wbf[1][c], a1, 0, 0, 0);
        }
#pragma unroll
        for (int r = 0; r < 4; ++r) {
          const int tr = t0 + q * 4 + r;
          sh.s.nr[tr][m]      = a0[r] + bb[0];
          sh.s.nr[tr][16 + m] = a1[r] + bb[1];
        }
      }
      __syncthreads();
    }
    float* outc = out + C_OFF + (size_t)b * L * (NUM_C * NUM_D);
    const int j4 = (tid & 7) * 4;
    for (int t = tid >> 3; t < L; t += 32) {
      const int c = sh.s.cb[t];
      float* oc = outc + (size_t)t * (NUM_C * NUM_D) + c * NUM_D + j4;
      *(f32x4*)oc = *(const f32x4*)&sh.s.nr[t][j4];
    }
    __threadfence();
    __syncthreads();
    if (tid == 0) atomicExch(&g_cflag[b], 1);
  } else {
    // ---------------- C_seq forward-fill (4 blocks/batch, 64 c's each) ----
    const int blk2 = blk - 64;
    const int b = blk2 >> 2, cbase = (blk2 & 3) * 64;
    if (tid < L) sh.f.cb[tid] = c_seq[b * L + tid];
    if (tid == 0) {
      while (atomicAdd(&g_cflag[b], 0) == 0) __builtin_amdgcn_s_sleep(32);
    }
    __syncthreads();
    __threadfence();
    // phase A: stage this block's update rows
    if (tid < L) {
      const int c = sh.f.cb[tid];
      if (c >= cbase && c < cbase + 64) {
        const float* src = out + C_OFF + ((size_t)b * L + tid) * (NUM_C * NUM_D) + (size_t)c * NUM_D;
#pragma unroll
        for (int j = 0; j < 8; ++j)
          *(f32x4*)&sh.f.stage[tid][j * 4] = *(const f32x4*)(src + j * 4);
      }
    }
    __syncthreads();
    // phase B: pure store loop (each thread owns 8 floats of one c-row)
    const int cl = tid >> 2, dq = (tid & 3) * 8;
    const int myc = cbase + cl;
    float* base = out + C_OFF + (size_t)b * L * (NUM_C * NUM_D) + (size_t)myc * NUM_D + dq;
    f32x4 cur0 = (f32x4)0.0f, cur1 = (f32x4)0.0f;
    for (int t = 0; t < L; ++t) {
      if (sh.f.cb[t] == myc) {
        cur0 = *(const f32x4*)&sh.f.stage[t][dq];
        cur1 = *(const f32x4*)&sh.f.stage[t][dq + 4];
      }
      *(f32x4*)base = cur0;
      *(f32x4*)(base + 4) = cur1;
      base += NUM_C * NUM_D;
    }
    // ---------------- then: one 64-row alpha tile (blocks 64..163) --------
    const int job = blk - 64;           // 0..99 valid; 100..127 exit
    if (job >= 100) return;
    if (tid == 0) {
      while (atomicAdd(&g_gcnt, 0) < 32) __builtin_amdgcn_s_sleep(32);
    }
    __syncthreads();                    // also separates sh.f use from sh.a
    __threadfence();
    {
      const int r0 = tid >> 2, kc = (tid & 3) * 32;
      cvt32(out + H_OFF + (size_t)(job * 64 + r0) * V + kc, &sh.a.hls[r0][kc]);
    }
    __syncthreads();
    f32x4 acc1[8];
#pragma unroll
    for (int i = 0; i < 8; ++i) acc1[i] = (f32x4)0.0f;
#pragma unroll
    for (int c = 0; c < 4; ++c) {
      const short8 af = *(const short8*)&sh.a.hls[w * 16 + m][32 * c + 8 * q];
#pragma unroll
      for (int i = 0; i < 8; ++i) {
        const short8 bf = ldfrag(W1a + (size_t)(i * 16 + m) * V + 32 * c + 8 * q);
        acc1[i] = __builtin_amdgcn_mfma_f32_16x16x32_bf16(af, bf, acc1[i], 0, 0, 0);
      }
    }
#pragma unroll
    for (int i = 0; i < 8; ++i) {
      const int col = i * 16 + m;
      const float bias = b1a[col];
#pragma unroll
      for (int r = 0; r < 4; ++r)
        sh.a.hid[w * 16 + q * 4 + r][col] = f2bf(fmaxf(acc1[i][r] + bias, 0.f));
    }
    __syncthreads();
    f32x4 acc2[2];
    acc2[0] = (f32x4)0.0f; acc2[1] = (f32x4)0.0f;
#pragma unroll
    for (int c = 0; c < 4; ++c) {
      const short8 af = *(const short8*)&sh.a.hid[w * 16 + m][32 * c + 8 * q];
#pragma unroll
      for (int tt = 0; tt < 2; ++tt) {
        const short8 bf = ldfrag(W1b + (size_t)(tt * 16 + m) * V + 32 * c + 8 * q);
        acc2[tt] = __builtin_amdgcn_mfma_f32_16x16x32_bf16(af, bf, acc2[tt], 0, 0, 0);
      }
    }
#pragma unroll
    for (int tt = 0; tt < 2; ++tt) {
      const int col = tt * 16 + m;
      const float bias = b1b[col];
#pragma unroll
      for (int r = 0; r < 4; ++r) {
        const int row = job * 64 + w * 16 + q * 4 + r;
        out[ALPHA_OFF + (size_t)row * NUM_D + col] = acc2[tt][r] + bias;
      }
    }
  }
}

extern "C" void kernel_launch(void* const* d_in, const int* in_sizes, int n_in,
                              void* d_out, int out_size, void* d_ws, size_t ws_size,
                              hipStream_t stream) {
  const int*   c_seq  = (const int*)d_in[0];
  const int*   d_seq  = (const int*)d_in[1];
  const float* r_seq  = (const float*)d_in[2];
  const float* X      = (const float*)d_in[3];
  const float* v_r    = (const float*)d_in[4];
  const float* v_beta = (const float*)d_in[5];
  const float* W_ih   = (const float*)d_in[6];
  const float* W_hh   = (const float*)d_in[7];
  const float* b_ih   = (const float*)d_in[8];
  const float* b_hh   = (const float*)d_in[9];
  const float* W1a    = (const float*)d_in[10];
  const float* b1a    = (const float*)d_in[11];
  const float* W1b    = (const float*)d_in[12];
  const float* b1b    = (const float*)d_in[13];
  const float* W2a    = (const float*)d_in[14];
  const float* b2a    = (const float*)d_in[15];
  const float* W2b    = (const float*)d_in[16];
  const float* b2b    = (const float*)d_in[17];
  float* out = (float*)d_out;
  float* Q = (float*)d_ws;

  k1<<<dim3(100, 8), 256, 0, stream>>>(c_seq, d_seq, r_seq, X, v_r, W_ih, W2a, b_ih, b2a, Q);
  k23<<<192, 256, 0, stream>>>(c_seq, d_seq, W_hh, b_hh, W2a, v_beta, W2b, b2b,
                               W1a, b1a, W1b, b1b, Q, out);
}

// Round 15
// 371.173 us; speedup vs baseline: 1.1150x; 1.0011x over previous
//
#include <hip/hip_runtime.h>
#include <hip/hip_bf16.h>

typedef unsigned short u16;
typedef unsigned int u32;
typedef short short8 __attribute__((ext_vector_type(8)));
typedef float f32x4 __attribute__((ext_vector_type(4)));

constexpr int BATCH = 32, L = 200, NUM_C = 256, NUM_D = 32, V = 128;
constexpr int G3 = 384;                 // 3*V
constexpr int KQ = 512;                 // Q row: 384 gx | 128 P
constexpr int ROWS = BATCH * L;         // 6400
constexpr int TP = 208;                 // padded t (13 tiles x 16)
constexpr size_t ALPHA_OFF = 0;
constexpr size_t H_OFF = (size_t)ROWS * NUM_D;        // 204800
constexpr size_t C_OFF = H_OFF + (size_t)ROWS * V;    // 1024000

// cross-block pipeline flags (zeroed by k1 each launch; k1 precedes in-stream)
__device__ int g_gcnt;        // GRU blocks finished
__device__ int g_cflag[32];   // per-batch: scan block done

__device__ inline u16 f2bf(float f) {
  __hip_bfloat16 h = __float2bfloat16(f);
  return __builtin_bit_cast(u16, h);
}
__device__ inline float bf2f(u16 u) { u32 x = ((u32)u) << 16; return __builtin_bit_cast(float, x); }

// convert 32 contiguous f32 -> 32 bf16 (dst 8B-aligned)
__device__ inline void cvt32(const float* __restrict__ src, u16* __restrict__ dst) {
#pragma unroll
  for (int j0 = 0; j0 < 32; j0 += 4) {
    const f32x4 v = *(const f32x4*)(src + j0);
    ushort4 s;
    s.x = f2bf(v[0]); s.y = f2bf(v[1]); s.z = f2bf(v[2]); s.w = f2bf(v[3]);
    *(ushort4*)(dst + j0) = s;
  }
}
// load 8 contiguous f32 -> bf16 MFMA fragment
__device__ inline short8 ldfrag(const float* __restrict__ p) {
  const f32x4 a = *(const f32x4*)p, b = *(const f32x4*)(p + 4);
  short8 s;
  s[0] = (short)f2bf(a[0]); s[1] = (short)f2bf(a[1]);
  s[2] = (short)f2bf(a[2]); s[3] = (short)f2bf(a[3]);
  s[4] = (short)f2bf(b[0]); s[5] = (short)f2bf(b[1]);
  s[6] = (short)f2bf(b[2]); s[7] = (short)f2bf(b[3]);
  return s;
}

// ---------------------------------------------------------------------------
// K1: Q[row, 0:384] = gru_in @ W_ih^T + b_ih ; Q[row, 384:512] = P (mem MLP)
//     (also zeroes the k23 pipeline flags)
// ---------------------------------------------------------------------------
__global__ __launch_bounds__(256) void k1(
    const int* __restrict__ c_seq, const int* __restrict__ d_seq,
    const float* __restrict__ r_seq, const float* __restrict__ X,
    const float* __restrict__ v_r, const float* __restrict__ W_ih,
    const float* __restrict__ W2a, const float* __restrict__ b_ih,
    const float* __restrict__ b2a, float* __restrict__ Qout)
{
  __shared__ __align__(16) u16 Als[64][144];
  __shared__ __align__(16) u16 Bls[64][144];
  const int tid = threadIdx.x;
  if (blockIdx.x == 0 && blockIdx.y == 0 && tid == 0) {
    g_gcnt = 0;
#pragma unroll
    for (int i = 0; i < 32; ++i) g_cflag[i] = 0;
  }
  const int mt = blockIdx.x, nt = blockIdx.y;
  const int lane = tid & 63, w = tid >> 6;
  const int q = lane >> 4, m = lane & 15;

  f32x4 acc[4];
#pragma unroll
  for (int i = 0; i < 4; ++i) acc[i] = (f32x4)0.0f;

  const int r0 = tid >> 2;          // 0..63 staged row
  const int kc = (tid & 3) * 32;    // k chunk
  const int rowg = mt * 64 + r0;    // global (b,t) row
  const int gcolB = nt * 64 + r0;   // global output col staged as B row

  for (int s = 0; s < 2; ++s) {     // two K-stages of 128
    if (s) __syncthreads();
    if (s == 0) {
      const int idx = c_seq[rowg] + NUM_C * d_seq[rowg];
      cvt32(X + (size_t)idx * V + kc, &Als[r0][kc]);
    } else {
      const float rv = r_seq[rowg];
#pragma unroll
      for (int j0 = 0; j0 < 32; j0 += 4) {
        const f32x4 v = *(const f32x4*)(v_r + kc + j0);
        ushort4 sv;
        sv.x = f2bf(rv * v[0]); sv.y = f2bf(rv * v[1]);
        sv.z = f2bf(rv * v[2]); sv.w = f2bf(rv * v[3]);
        *(ushort4*)&Als[r0][kc + j0] = sv;
      }
    }
    {
      const float* src = (gcolB < G3)
        ? (W_ih + (size_t)gcolB * 256 + s * 128 + kc)
        : (W2a + (size_t)(gcolB - G3) * G3 + V + s * 128 + kc);
      cvt32(src, &Bls[r0][kc]);
    }
    __syncthreads();
#pragma unroll
    for (int c = 0; c < 4; ++c) {
      const short8 af = *(const short8*)&Als[w * 16 + m][32 * c + 8 * q];
#pragma unroll
      for (int i = 0; i < 4; ++i) {
        const short8 bf = *(const short8*)&Bls[i * 16 + m][32 * c + 8 * q];
        acc[i] = __builtin_amdgcn_mfma_f32_16x16x32_bf16(af, bf, acc[i], 0, 0, 0);
      }
    }
  }
#pragma unroll
  for (int i = 0; i < 4; ++i) {
    const int col = nt * 64 + i * 16 + m;
    const float bias = (col < G3) ? b_ih[col] : b2a[col - G3];
#pragma unroll
    for (int r = 0; r < 4; ++r) {
      const int rowo = mt * 64 + w * 16 + q * 4 + r;
      Qout[(size_t)rowo * KQ + col] = acc[i][r] + bias;
    }
  }
}

// ---------------------------------------------------------------------------
// K23 (fused, flag-pipelined) — PRIVATE-CU layout (LDS>80KB -> 1 block/CU;
// 192 blocks <= 256 CUs -> all resident by capacity, spin-wait safe):
//   blocks   0.. 31: GRU batch b -> g_gcnt++ (h in LDS hbuf, one flush;
//                    depth-4 gx banks).
//   blocks  32.. 63: memory-scan parallel fixpoint -> g_cflag[b]=1
//   blocks  64..191: C_seq forward-fill (4/batch), waits g_cflag[b].
//                    NEW vs r14: s_sleep(8) per store iteration RATE-LIMITS
//                    the 210MB burst (~40us -> ~85us window, half the
//                    instantaneous store rate) so the GRU's loads see less
//                    L2/HBM queue congestion. Fill has >>50us slack before
//                    its alpha job needs g_gcnt==32.
//                    Blocks 64..163 then run ONE 64-row alpha tile.
// ---------------------------------------------------------------------------
union ShK23 {
  struct { u16 h_bf[2][V]; float hbuf[L][V]; } g;   // 0.5KB + 102.4KB
  struct {
    int cb[TP]; int db[TP]; int sp[TP];
    float nr[TP][36];                 // n(t) rows; stride 36 (16B-aligned)
    float u[V];
    int maxd;
  } s;
  struct { int cb[L]; float stage[L][NUM_D]; } f;
  struct { u16 hls[64][144]; u16 hid[64][144]; } a;
  struct { char p[84000]; } pad;      // floor: keeps 1 block/CU even if g shrinks
};

__global__ __launch_bounds__(256, 1) void k23(
    const int* __restrict__ c_seq, const int* __restrict__ d_seq,
    const float* __restrict__ W_hh, const float* __restrict__ b_hh,
    const float* __restrict__ W2a, const float* __restrict__ v_beta,
    const float* __restrict__ W2b, const float* __restrict__ b2b,
    const float* __restrict__ W1a, const float* __restrict__ b1a,
    const float* __restrict__ W1b, const float* __restrict__ b1b,
    const float* __restrict__ Q, float* __restrict__ out)
{
  __shared__ __align__(16) ShK23 sh;
  const int tid = threadIdx.x;
  const int l = tid & 63, w = tid >> 6, q = l >> 4, m = l & 15;
  const int blk = blockIdx.x;

  if (blk < 32) {
    // ---------------- GRU (r14 loop, verbatim) ----------------------------
    const int b = blk;
    if (tid < V) sh.g.h_bf[0][tid] = 0;
    __syncthreads();
    short8 wf[6][4];
    float bhh[6]; int gcol[6];
#pragma unroll
    for (int i = 0; i < 6; ++i) {
      const int g = (w + 4 * i) * 16 + m;
      gcol[i] = g;
      bhh[i] = b_hh[g];
#pragma unroll
      for (int c = 0; c < 4; ++c)
        wf[i][c] = ldfrag(W_hh + (size_t)g * V + 32 * c + 8 * q);
    }
    const float* Qb = Q + (size_t)b * L * KQ;
    float* outh = out + H_OFF + (size_t)b * L * V;
    const int vi0 = 16 * w + m, vi1 = 64 + 16 * w + m;
    float hold[2] = {0.f, 0.f};
    const f32x4 z4 = (f32x4)0.0f;
    float gxA[6], gxB[6], gxC[6], gxD[6];
#pragma unroll
    for (int i = 0; i < 6; ++i) gxA[i] = Qb[gcol[i]];
#pragma unroll
    for (int i = 0; i < 6; ++i) gxB[i] = Qb[KQ + gcol[i]];
#pragma unroll
    for (int i = 0; i < 6; ++i) gxC[i] = Qb[2 * KQ + gcol[i]];
#pragma unroll
    for (int i = 0; i < 6; ++i) gxD[i] = Qb[3 * KQ + gcol[i]];

    auto step = [&](int t, float (&gx)[6]) {
      const int rs = t & 1, wsl = rs ^ 1;
      short8 af[4];
#pragma unroll
      for (int c = 0; c < 4; ++c)
        af[c] = *(const short8*)&sh.g.h_bf[rs][32 * c + 8 * q];
      f32x4 acc[6];
#pragma unroll
      for (int i = 0; i < 6; ++i)
        acc[i] = __builtin_amdgcn_mfma_f32_16x16x32_bf16(af[0], wf[i][0], z4, 0, 0, 0);
#pragma unroll
      for (int c = 1; c < 4; ++c)
#pragma unroll
        for (int i = 0; i < 6; ++i)
          acc[i] = __builtin_amdgcn_mfma_f32_16x16x32_bf16(af[c], wf[i][c], acc[i], 0, 0, 0);
      float hnew[2];
#pragma unroll
      for (int s = 0; s < 2; ++s) {
        const float xr = gx[0 + s] + acc[0 + s][0] + bhh[0 + s];
        const float xz = gx[2 + s] + acc[2 + s][0] + bhh[2 + s];
        const float ghn = acc[4 + s][0] + bhh[4 + s];
        const float r = 1.f / (1.f + __expf(-xr));
        const float z = 1.f / (1.f + __expf(-xz));
        const float xn = gx[4 + s] + r * ghn;
        const float e = __expf(2.f * xn);
        const float n = 1.f - 2.f / (e + 1.f);     // tanh(xn)
        hnew[s] = (1.f - z) * n + z * hold[s];
      }
      if (q == 0) {
        sh.g.h_bf[wsl][vi0] = f2bf(hnew[0]);
        sh.g.h_bf[wsl][vi1] = f2bf(hnew[1]);
        sh.g.hbuf[t][vi0] = hnew[0];      // LDS h buffer (no global store)
        sh.g.hbuf[t][vi1] = hnew[1];
      }
      hold[0] = hnew[0]; hold[1] = hnew[1];
      if (t + 4 < L) {                    // reload this bank for t+4
        const float* Qr = Qb + (size_t)(t + 4) * KQ;
#pragma unroll
        for (int i = 0; i < 6; ++i) gx[i] = Qr[gcol[i]];
      }
      __builtin_amdgcn_s_waitcnt(0xc07f);   // lgkmcnt(0)
      __builtin_amdgcn_s_barrier();
    };

    for (int t = 0; t < L; t += 4) {
      step(t, gxA);
      step(t + 1, gxB);
      step(t + 2, gxC);
      step(t + 3, gxD);
    }
    // flush h buffer -> global (coalesced, one burst, ~102KB)
    {
      const f32x4* src = (const f32x4*)&sh.g.hbuf[0][0];
      f32x4* dst = (f32x4*)outh;
      for (int i = tid; i < L * V / 4; i += 256) dst[i] = src[i];
    }
    __threadfence();
    __syncthreads();
    if (tid == 0) atomicAdd(&g_gcnt, 1);
  } else if (blk < 64) {
    // ---------------- memory scan: parallel fixpoint (round-8) ------------
    const int b = blk - 32;
    for (int i = tid; i < TP; i += 256) {
      int c = -1, d = 0;
      if (i < L) { c = c_seq[b * L + i]; d = d_seq[b * L + i]; }
      sh.s.cb[i] = c; sh.s.db[i] = d; sh.s.sp[i] = -1;
    }
    if (tid < V) {
      float a = 0.f;
      const float* wr = W2a + (size_t)tid * G3;
      for (int k = 0; k < V; ++k) a += wr[k] * v_beta[k];
      sh.s.u[tid] = a;
    }
    if (tid == 0) sh.s.maxd = 0;
    __syncthreads();
    {
      const int c = tid;               // 256 threads == NUM_C
      int prev = -1;
      for (int t4 = 0; t4 < L; t4 += 4) {
        const int4 v = *(const int4*)&sh.s.cb[t4];
        if (v.x == c) { sh.s.sp[t4 + 0] = prev; prev = t4 + 0; }
        if (v.y == c) { sh.s.sp[t4 + 1] = prev; prev = t4 + 1; }
        if (v.z == c) { sh.s.sp[t4 + 2] = prev; prev = t4 + 2; }
        if (v.w == c) { sh.s.sp[t4 + 3] = prev; prev = t4 + 3; }
      }
    }
    __syncthreads();
    {
      int dmx = 0;
      for (int t = tid; t < L; t += 256) {
        int dd = 0, s = sh.s.sp[t];
        while (s >= 0) { ++dd; s = sh.s.sp[s]; }
        dmx = dmx > dd ? dmx : dd;
      }
      atomicMax(&sh.s.maxd, dmx);
    }
    __syncthreads();
    const int rounds = sh.s.maxd + 1;
    float ureg[4][8];
#pragma unroll
    for (int c = 0; c < 4; ++c)
#pragma unroll
      for (int j = 0; j < 8; ++j) ureg[c][j] = sh.s.u[32 * c + 8 * q + j];
    short8 wbf[2][4];
    float bb[2];
#pragma unroll
    for (int tt = 0; tt < 2; ++tt) {
#pragma unroll
      for (int c = 0; c < 4; ++c)
        wbf[tt][c] = ldfrag(W2b + (size_t)(tt * 16 + m) * V + 32 * c + 8 * q);
      bb[tt] = b2b[tt * 16 + m];
    }
    const f32x4 z4 = (f32x4)0.0f;
    for (int rd = 0; rd < rounds; ++rd) {
      for (int ti = w; ti < 13; ti += 4) {
        const int t0 = ti * 16;
        const int tt = t0 + m;
        const bool ok = tt < L;
        const int spv = ok ? sh.s.sp[tt] : -1;
        const int dbv = ok ? sh.s.db[tt] : 0;
        const float beta = (spv >= 0) ? sh.s.nr[spv][dbv] : 0.f;
        const float* pr = Q + ((size_t)b * L + tt) * KQ + G3 + 8 * q;
        short8 af[4];
#pragma unroll
        for (int c = 0; c < 4; ++c) {
          const f32x4 p0 = ok ? *(const f32x4*)(pr + 32 * c) : (f32x4)0.0f;
          const f32x4 p1 = ok ? *(const f32x4*)(pr + 32 * c + 4) : (f32x4)0.0f;
          short8 a;
#pragma unroll
          for (int j = 0; j < 8; ++j) {
            const float pv = (j < 4) ? p0[j] : p1[j - 4];
            a[j] = (short)f2bf(fmaxf(beta * ureg[c][j] + pv, 0.f));
          }
          af[c] = a;
        }
        f32x4 a0 = z4, a1 = z4;
#pragma unroll
        for (int c = 0; c < 4; ++c) {
          a0 = __builtin_amdgcn_mfma_f32_16x16x32_bf16(af[c], wbf[0][c], a0, 0, 0, 0);
          a1 = __builtin_amdgcn_mfma_f32_16x16x32_bf16(af[c], wbf[1][c], a1, 0, 0, 0);
        }
#pragma unroll
        for (int r = 0; r < 4; ++r) {
          const int tr = t0 + q * 4 + r;
          sh.s.nr[tr][m]      = a0[r] + bb[0];
          sh.s.nr[tr][16 + m] = a1[r] + bb[1];
        }
      }
      __syncthreads();
    }
    float* outc = out + C_OFF + (size_t)b * L * (NUM_C * NUM_D);
    const int j4 = (tid & 7) * 4;
    for (int t = tid >> 3; t < L; t += 32) {
      const int c = sh.s.cb[t];
      float* oc = outc + (size_t)t * (NUM_C * NUM_D) + c * NUM_D + j4;
      *(f32x4*)oc = *(const f32x4*)&sh.s.nr[t][j4];
    }
    __threadfence();
    __syncthreads();
    if (tid == 0) atomicExch(&g_cflag[b], 1);
  } else {
    // ---------------- C_seq forward-fill (4 blocks/batch, 64 c's each) ----
    const int blk2 = blk - 64;
    const int b = blk2 >> 2, cbase = (blk2 & 3) * 64;
    if (tid < L) sh.f.cb[tid] = c_seq[b * L + tid];
    if (tid == 0) {
      while (atomicAdd(&g_cflag[b], 0) == 0) __builtin_amdgcn_s_sleep(32);
    }
    __syncthreads();
    __threadfence();
    // phase A: stage this block's update rows
    if (tid < L) {
      const int c = sh.f.cb[tid];
      if (c >= cbase && c < cbase + 64) {
        const float* src = out + C_OFF + ((size_t)b * L + tid) * (NUM_C * NUM_D) + (size_t)c * NUM_D;
#pragma unroll
        for (int j = 0; j < 8; ++j)
          *(f32x4*)&sh.f.stage[tid][j * 4] = *(const f32x4*)(src + j * 4);
      }
    }
    __syncthreads();
    // phase B: RATE-LIMITED store loop (s_sleep(8)/iter halves the
    // instantaneous store rate; total window ~85us << GRU's ~146us)
    const int cl = tid >> 2, dq = (tid & 3) * 8;
    const int myc = cbase + cl;
    float* base = out + C_OFF + (size_t)b * L * (NUM_C * NUM_D) + (size_t)myc * NUM_D + dq;
    f32x4 cur0 = (f32x4)0.0f, cur1 = (f32x4)0.0f;
    for (int t = 0; t < L; ++t) {
      if (sh.f.cb[t] == myc) {
        cur0 = *(const f32x4*)&sh.f.stage[t][dq];
        cur1 = *(const f32x4*)&sh.f.stage[t][dq + 4];
      }
      *(f32x4*)base = cur0;
      *(f32x4*)(base + 4) = cur1;
      base += NUM_C * NUM_D;
      __builtin_amdgcn_s_sleep(8);
    }
    // ---------------- then: one 64-row alpha tile (blocks 64..163) --------
    const int job = blk - 64;           // 0..99 valid; 100..127 exit
    if (job >= 100) return;
    if (tid == 0) {
      while (atomicAdd(&g_gcnt, 0) < 32) __builtin_amdgcn_s_sleep(32);
    }
    __syncthreads();                    // also separates sh.f use from sh.a
    __threadfence();
    {
      const int r0 = tid >> 2, kc = (tid & 3) * 32;
      cvt32(out + H_OFF + (size_t)(job * 64 + r0) * V + kc, &sh.a.hls[r0][kc]);
    }
    __syncthreads();
    f32x4 acc1[8];
#pragma unroll
    for (int i = 0; i < 8; ++i) acc1[i] = (f32x4)0.0f;
#pragma unroll
    for (int c = 0; c < 4; ++c) {
      const short8 af = *(const short8*)&sh.a.hls[w * 16 + m][32 * c + 8 * q];
#pragma unroll
      for (int i = 0; i < 8; ++i) {
        const short8 bf = ldfrag(W1a + (size_t)(i * 16 + m) * V + 32 * c + 8 * q);
        acc1[i] = __builtin_amdgcn_mfma_f32_16x16x32_bf16(af, bf, acc1[i], 0, 0, 0);
      }
    }
#pragma unroll
    for (int i = 0; i < 8; ++i) {
      const int col = i * 16 + m;
      const float bias = b1a[col];
#pragma unroll
      for (int r = 0; r < 4; ++r)
        sh.a.hid[w * 16 + q * 4 + r][col] = f2bf(fmaxf(acc1[i][r] + bias, 0.f));
    }
    __syncthreads();
    f32x4 acc2[2];
    acc2[0] = (f32x4)0.0f; acc2[1] = (f32x4)0.0f;
#pragma unroll
    for (int c = 0; c < 4; ++c) {
      const short8 af = *(const short8*)&sh.a.hid[w * 16 + m][32 * c + 8 * q];
#pragma unroll
      for (int tt = 0; tt < 2; ++tt) {
        const short8 bf = ldfrag(W1b + (size_t)(tt * 16 + m) * V + 32 * c + 8 * q);
        acc2[tt] = __builtin_amdgcn_mfma_f32_16x16x32_bf16(af, bf, acc2[tt], 0, 0, 0);
      }
    }
#pragma unroll
    for (int tt = 0; tt < 2; ++tt) {
      const int col = tt * 16 + m;
      const float bias = b1b[col];
#pragma unroll
      for (int r = 0; r < 4; ++r) {
        const int row = job * 64 + w * 16 + q * 4 + r;
        out[ALPHA_OFF + (size_t)row * NUM_D + col] = acc2[tt][r] + bias;
      }
    }
  }
}

extern "C" void kernel_launch(void* const* d_in, const int* in_sizes, int n_in,
                              void* d_out, int out_size, void* d_ws, size_t ws_size,
                              hipStream_t stream) {
  const int*   c_seq  = (const int*)d_in[0];
  const int*   d_seq  = (const int*)d_in[1];
  const float* r_seq  = (const float*)d_in[2];
  const float* X      = (const float*)d_in[3];
  const float* v_r    = (const float*)d_in[4];
  const float* v_beta = (const float*)d_in[5];
  const float* W_ih   = (const float*)d_in[6];
  const float* W_hh   = (const float*)d_in[7];
  const float* b_ih   = (const float*)d_in[8];
  const float* b_hh   = (const float*)d_in[9];
  const float* W1a    = (const float*)d_in[10];
  const float* b1a    = (const float*)d_in[11];
  const float* W1b    = (const float*)d_in[12];
  const float* b1b    = (const float*)d_in[13];
  const float* W2a    = (const float*)d_in[14];
  const float* b2a    = (const float*)d_in[15];
  const float* W2b    = (const float*)d_in[16];
  const float* b2b    = (const float*)d_in[17];
  float* out = (float*)d_out;
  float* Q = (float*)d_ws;

  k1<<<dim3(100, 8), 256, 0, stream>>>(c_seq, d_seq, r_seq, X, v_r, W_ih, W2a, b_ih, b2a, Q);
  k23<<<192, 256, 0, stream>>>(c_seq, d_seq, W_hh, b_hh, W2a, v_beta, W2b, b2b,
                               W1a, b1a, W1b, b1b, Q, out);
}